// Round 3
// baseline (6159.024 us; speedup 1.0000x reference)
//
#include <hip/hip_runtime.h>
#include <hip/hip_bf16.h>
#include <math.h>

typedef short s16x8 __attribute__((ext_vector_type(8)));
typedef float f32x4 __attribute__((ext_vector_type(4)));
typedef unsigned short u16;

// ---------- helpers ----------
__device__ __forceinline__ u16 f2b(float f) {
    unsigned u = __builtin_bit_cast(unsigned, f);
    u += 0x7fffu + ((u >> 16) & 1u);           // round-to-nearest-even
    return (u16)(u >> 16);
}
__device__ __forceinline__ f32x4 mfma16(s16x8 a, s16x8 b, f32x4 c) {
    return __builtin_amdgcn_mfma_f32_16x16x32_bf16(a, b, c, 0, 0, 0);
}
__device__ __forceinline__ void gload16(const void* g, void* l) {
    __builtin_amdgcn_global_load_lds((const __attribute__((address_space(1))) unsigned*)g,
                                     (__attribute__((address_space(3))) unsigned*)l, 16, 0, 0);
}

// ---------- patchify: x (32,64,32,32) f32 -> patchA (8192,256) bf16 ----------
__global__ __launch_bounds__(256) void patchify_kernel(const float* __restrict__ x, u16* __restrict__ out) {
    int idx = blockIdx.x * 256 + threadIdx.x;
    int row = idx >> 8, col = idx & 255;
    int b = row >> 8, ll = row & 255, hp = ll >> 4, wp = ll & 15;
    int pp = col >> 6, d = col & 63;
    out[idx] = f2b(x[(size_t)((b * 64 + d) * 32 + hp * 2 + (pp >> 1)) * 32 + wp * 2 + (pp & 1)]);
}

// ---------- c_act = silu(timestep_emb + emb_table[y]) -> f32 (32,1024) ----------
__global__ __launch_bounds__(256) void cact_kernel(const int* __restrict__ t, const int* __restrict__ y,
                                                   const float* __restrict__ emb, float* __restrict__ cactF) {
    int b = blockIdx.x, tid = threadIdx.x;
    float tv = (float)t[b];
    int yb = y[b];
#pragma unroll
    for (int j = 0; j < 4; ++j) {
        int c = tid * 4 + j;
        int f = (c < 512) ? c : c - 512;
        float freq = __expf(-9.210340371976184f * (float)f * (1.f / 512.f));
        float ang = tv * freq;
        float v = (c < 512) ? cosf(ang) : sinf(ang);
        v += emb[(size_t)yb * 1024 + c];
        v = v / (1.f + __expf(-v));   // silu
        cactF[b * 1024 + c] = v;
    }
}

// ---------- concat q/k/v biases for all 12 layers -> (12,3072) f32 ----------
__global__ __launch_bounds__(256) void bcat_kernel(const float* __restrict__ bq, const float* __restrict__ bk,
                                                   const float* __restrict__ bv, float* __restrict__ out) {
    int lyr = blockIdx.x, j = blockIdx.y, tid = threadIdx.x;
    const float* src = (j == 0) ? bq : ((j == 1) ? bk : bv);
    float4 v = ((const float4*)(src + (size_t)lyr * 1024))[tid];
    ((float4*)(out + (size_t)lyr * 3072 + j * 1024))[tid] = v;
}

// ---------- mod32: out(32,N) = cactF(32,1024) @ W(1024,N) + bias, all f32 ----------
// grid N/64 blocks, 256 thr: lane->n, wave->k-quarter; c chunks staged in LDS.
__global__ __launch_bounds__(256) void mod32_kernel(const float* __restrict__ cactF, const float* __restrict__ W,
                                                    const float* __restrict__ bias, float* __restrict__ out, int N) {
    __shared__ float cs[32 * 256];
    __shared__ float red[4 * 32 * 64];
    int tid = threadIdx.x, lane = tid & 63, kg = tid >> 6;
    int n = blockIdx.x * 64 + lane;
    float acc[32];
#pragma unroll
    for (int r = 0; r < 32; ++r) acc[r] = 0.f;
    for (int ch = 0; ch < 4; ++ch) {
        __syncthreads();
#pragma unroll
        for (int j = 0; j < 8; ++j) {
            int idx = tid * 4 + j * 1024;
            float4 v = *(const float4*)&cactF[(size_t)(idx >> 8) * 1024 + ch * 256 + (idx & 255)];
            *(float4*)&cs[idx] = v;
        }
        __syncthreads();
        const float* Wp = W + (size_t)(ch * 256 + kg * 64) * N + n;
        for (int kk = 0; kk < 64; kk += 4) {
            float w0 = Wp[(size_t)(kk + 0) * N];
            float w1 = Wp[(size_t)(kk + 1) * N];
            float w2 = Wp[(size_t)(kk + 2) * N];
            float w3 = Wp[(size_t)(kk + 3) * N];
            int kb = kg * 64 + kk;
#pragma unroll
            for (int r = 0; r < 32; ++r) {
                float4 cv = *(const float4*)&cs[r * 256 + kb];
                acc[r] += cv.x * w0 + cv.y * w1 + cv.z * w2 + cv.w * w3;
            }
        }
    }
#pragma unroll
    for (int r = 0; r < 32; ++r) red[(kg * 32 + r) * 64 + lane] = acc[r];
    __syncthreads();
    int r = tid >> 3, j0 = (tid & 7) * 8;
#pragma unroll
    for (int jj = 0; jj < 8; ++jj) {
        int nn = j0 + jj;
        float s = red[(0 * 32 + r) * 64 + nn] + red[(1 * 32 + r) * 64 + nn] +
                  red[(2 * 32 + r) * 64 + nn] + red[(3 * 32 + r) * 64 + nn];
        out[(size_t)r * N + blockIdx.x * 64 + nn] = s + bias[blockIdx.x * 64 + nn];
    }
}

// ---------- 64x64 transpose + f32->bf16 convert body ----------
__device__ __forceinline__ void tpose_body(float (*tile)[65], const float* __restrict__ in,
                                           u16* __restrict__ out, int R, int C, int r0, int c0, int tid) {
    int rr = tid >> 4, cc = (tid & 15) * 4;
#pragma unroll
    for (int j = 0; j < 4; ++j) {
        float4 v = *(const float4*)&in[(size_t)(r0 + j * 16 + rr) * C + c0 + cc];
        tile[j * 16 + rr][cc]     = v.x;
        tile[j * 16 + rr][cc + 1] = v.y;
        tile[j * 16 + rr][cc + 2] = v.z;
        tile[j * 16 + rr][cc + 3] = v.w;
    }
    __syncthreads();
    int oc = tid >> 3, r8 = (tid & 7) * 8;
#pragma unroll
    for (int j = 0; j < 2; ++j) {
        int ocl = j * 32 + oc;
        s16x8 vv;
#pragma unroll
        for (int e = 0; e < 8; ++e) vv[e] = (short)f2b(tile[r8 + e][ocl]);
        *(s16x8*)&out[(size_t)(c0 + ocl) * R + r0 + r8] = vv;
    }
}

__global__ __launch_bounds__(256) void transpose_cvt64k(const float* __restrict__ in, u16* __restrict__ out,
                                                        int R, int C) {
    __shared__ float tile[64][65];
    tpose_body(tile, in, out, R, C, blockIdx.y * 64, blockIdx.x * 64, threadIdx.x);
}

// ---------- one layer's attention/MLP weights, transposed+converted ----------
__global__ __launch_bounds__(256) void transpose_layer(
    const float* __restrict__ wq, const float* __restrict__ wk,
    const float* __restrict__ wv, const float* __restrict__ wo, const float* __restrict__ f1,
    const float* __restrict__ f2,
    u16* __restrict__ qkvT, u16* __restrict__ woT, u16* __restrict__ f1T, u16* __restrict__ f2T) {
    __shared__ float tile[64][65];
    int bid = blockIdx.x, tid = threadIdx.x;
    const float* src; u16* dst; int R, C, tloc;
    if (bid < 256)       { src = wq; dst = qkvT;               R = 1024; C = 1024; tloc = bid; }
    else if (bid < 512)  { src = wk; dst = qkvT + 1024 * 1024; R = 1024; C = 1024; tloc = bid - 256; }
    else if (bid < 768)  { src = wv; dst = qkvT + 2048 * 1024; R = 1024; C = 1024; tloc = bid - 512; }
    else if (bid < 1024) { src = wo; dst = woT;                R = 1024; C = 1024; tloc = bid - 768; }
    else if (bid < 2048) { src = f1; dst = f1T;                R = 1024; C = 4096; tloc = bid - 1024; }
    else                 { src = f2; dst = f2T;                R = 4096; C = 1024; tloc = bid - 2048; }
    int tx = C >> 6;
    int ty = tloc / tx, txi = tloc - ty * tx;
    tpose_body(tile, src, dst, R, C, ty * 64, txi * 64, tid);
}

// ---------- LayerNorm + modulate: hx = ln(x)*(1+sc)+sh -> bf16 ----------
__global__ __launch_bounds__(256) void ln_mod_kernel(const float* __restrict__ x, const float* __restrict__ modv,
                                                     int mod_ld, int sh_off, int sc_off, u16* __restrict__ out) {
    int row = blockIdx.x, tid = threadIdx.x, b = row >> 8;
    float4 xv = ((const float4*)(x + (size_t)row * 1024))[tid];
    float s = xv.x + xv.y + xv.z + xv.w;
    float s2 = xv.x * xv.x + xv.y * xv.y + xv.z * xv.z + xv.w * xv.w;
#pragma unroll
    for (int d = 1; d < 64; d <<= 1) { s += __shfl_xor(s, d); s2 += __shfl_xor(s2, d); }
    __shared__ float red[8];
    int w = tid >> 6;
    if ((tid & 63) == 0) { red[w] = s; red[4 + w] = s2; }
    __syncthreads();
    s = red[0] + red[1] + red[2] + red[3];
    s2 = red[4] + red[5] + red[6] + red[7];
    float mu = s * (1.f / 1024.f);
    float rs = rsqrtf(s2 * (1.f / 1024.f) - mu * mu + 1e-5f);
    const float* shp = modv + (size_t)b * mod_ld + sh_off;
    const float* scp = modv + (size_t)b * mod_ld + sc_off;
    float4 sh4 = ((const float4*)shp)[tid];
    float4 sc4 = ((const float4*)scp)[tid];
    u16 o0 = f2b((xv.x - mu) * rs * (1.f + sc4.x) + sh4.x);
    u16 o1 = f2b((xv.y - mu) * rs * (1.f + sc4.y) + sh4.y);
    u16 o2 = f2b((xv.z - mu) * rs * (1.f + sc4.z) + sh4.z);
    u16 o3 = f2b((xv.w - mu) * rs * (1.f + sc4.w) + sh4.w);
    unsigned long long pk = (unsigned long long)o0 | ((unsigned long long)o1 << 16) |
                            ((unsigned long long)o2 << 32) | ((unsigned long long)o3 << 48);
    *(unsigned long long*)&out[(size_t)row * 1024 + tid * 4] = pk;
}

// =====================================================================
// gemm256: 256x256 tile, BK=32, 512 thr (8 waves 4Mx2N, 64x128/wave),
// 3 LDS buffers (96KB), counted vmcnt(4), granule swizzle g ^= (r>>1)&3.
// C = A(MxK) * Bt(NxK)^T, bf16 in. M%256==0, N%256==0, K%64==0, grid%8==0.
// EPI 1: bf16 + bias; EPI 4: gelu bf16
// =====================================================================
template <int EPI>
__global__ __launch_bounds__(512, 1) void gemm256(
    const u16* __restrict__ A, int lda, const u16* __restrict__ Bt, int ldb,
    int M, int N, int K, const float* __restrict__ bias, u16* __restrict__ outB, int ldc) {
    __shared__ u16 As[3][256 * 32];
    __shared__ u16 Bs[3][256 * 32];

    const int tid = threadIdx.x, w = tid >> 6, l = tid & 63;
    const int wm = w >> 1, wn = w & 1;
    const int fr = l & 15, fg = l >> 4;

    const int nbn = N >> 8;
    const int orig = blockIdx.x;
    const int cpx = gridDim.x >> 3;
    const int wg = (orig & 7) * cpx + (orig >> 3);   // XCD-chunked swizzle
    const int bm = wg / nbn, bn = wg - bm * nbn;
    const int row0 = bm << 8, col0 = bn << 8;
    const int NT = K >> 5;

    // staging: thread -> (srow 0..127, slot 0..3); rounds add 128 rows.
    const int srow = tid >> 2, slot = tid & 3;
    const int gs = slot ^ ((srow >> 1) & 3);         // global granule for this LDS slot
    const u16* gA = A + (size_t)(row0 + srow) * lda + gs * 8;
    const u16* gB = Bt + (size_t)(col0 + srow) * ldb + gs * 8;

    // fragment ds offsets (elements), swizzled
    int aoff[4], boff[8];
#pragma unroll
    for (int m = 0; m < 4; ++m) {
        int rr = wm * 64 + m * 16 + fr;
        aoff[m] = rr * 32 + ((fg ^ ((rr >> 1) & 3)) * 8);
    }
#pragma unroll
    for (int j = 0; j < 8; ++j) {
        int rr = wn * 128 + j * 16 + fr;
        boff[j] = rr * 32 + ((fg ^ ((rr >> 1) & 3)) * 8);
    }

    f32x4 acc[4][8];
#pragma unroll
    for (int m = 0; m < 4; ++m)
#pragma unroll
        for (int j = 0; j < 8; ++j) acc[m][j] = (f32x4){0.f, 0.f, 0.f, 0.f};

    // prologue: stage tile0 -> buf0, tile1 -> buf1
    {
        u16* d0 = &As[0][tid * 8];
        gload16(gA, d0); gload16(gA + (size_t)128 * lda, d0 + 4096);
        u16* e0 = &Bs[0][tid * 8];
        gload16(gB, e0); gload16(gB + (size_t)128 * ldb, e0 + 4096);
        u16* d1 = &As[1][tid * 8];
        gload16(gA + 32, d1); gload16(gA + (size_t)128 * lda + 32, d1 + 4096);
        u16* e1 = &Bs[1][tid * 8];
        gload16(gB + 32, e1); gload16(gB + (size_t)128 * ldb + 32, e1 + 4096);
    }
    asm volatile("s_waitcnt vmcnt(4)" ::: "memory");
    __builtin_amdgcn_s_barrier();
    __builtin_amdgcn_sched_barrier(0);

    int q = 0;
    for (int t = 0; t < NT; ++t) {
        const u16* ca = As[q];
        const u16* cb = Bs[q];
        const int q1 = (q == 2) ? 0 : q + 1;
        const int q2 = (q1 == 2) ? 0 : q1 + 1;

        s16x8 af[4], bfv[4];
        // ---- phase 0: read A frags + B[0..3]; stage A of t+2 ----
#pragma unroll
        for (int m = 0; m < 4; ++m) af[m] = *(const s16x8*)(ca + aoff[m]);
#pragma unroll
        for (int j = 0; j < 4; ++j) bfv[j] = *(const s16x8*)(cb + boff[j]);
        if (t + 2 < NT) {
            u16* d = &As[q2][tid * 8];
            const u16* s = gA + (size_t)(t + 2) * 32;
            gload16(s, d); gload16(s + (size_t)128 * lda, d + 4096);
        }
        __builtin_amdgcn_s_barrier();
        __builtin_amdgcn_s_setprio(1);
#pragma unroll
        for (int m = 0; m < 4; ++m)
#pragma unroll
            for (int j = 0; j < 4; ++j) acc[m][j] = mfma16(af[m], bfv[j], acc[m][j]);
        __builtin_amdgcn_s_setprio(0);
        __builtin_amdgcn_s_barrier();
        // ---- phase 1: read B[4..7]; stage B of t+2 ----
#pragma unroll
        for (int j = 0; j < 4; ++j) bfv[j] = *(const s16x8*)(cb + boff[j + 4]);
        if (t + 2 < NT) {
            u16* d = &Bs[q2][tid * 8];
            const u16* s = gB + (size_t)(t + 2) * 32;
            gload16(s, d); gload16(s + (size_t)128 * ldb, d + 4096);
        }
        __builtin_amdgcn_s_setprio(1);
#pragma unroll
        for (int m = 0; m < 4; ++m)
#pragma unroll
            for (int j = 0; j < 4; ++j) acc[m][j + 4] = mfma16(af[m], bfv[j], acc[m][j + 4]);
        __builtin_amdgcn_s_setprio(0);
        // ---- tile boundary ----
        if (t < NT - 2)       { asm volatile("s_waitcnt vmcnt(4)" ::: "memory"); }
        else if (t == NT - 2) { asm volatile("s_waitcnt vmcnt(0)" ::: "memory"); }
        if (t < NT - 1) {
            __builtin_amdgcn_s_barrier();
            __builtin_amdgcn_sched_barrier(0);
        }
        q = q1;
    }

    // epilogue
    const int erow = row0 + wm * 64 + fg * 4;
    const int ecol = col0 + wn * 128 + fr;
#pragma unroll
    for (int m = 0; m < 4; ++m) {
#pragma unroll
        for (int j = 0; j < 8; ++j) {
#pragma unroll
            for (int r = 0; r < 4; ++r) {
                int row = erow + m * 16 + r;
                int col = ecol + j * 16;
                float v = acc[m][j][r] + bias[col];
                if constexpr (EPI == 1) {
                    outB[(size_t)row * ldc + col] = f2b(v);
                } else {  // EPI == 4: exact gelu
                    outB[(size_t)row * ldc + col] = f2b(0.5f * v * (1.f + erff(v * 0.70710678118654752f)));
                }
            }
        }
    }
}

// =====================================================================
// gemm8: pipelined GEMM, BM=256 x BN=128, BK=64, 512 thr (8 waves 4x2),
// 3 LDS buffers, counted vmcnt, granule swizzle g ^= r&7 (8-slot spread).
// EPI: 2 f32+bias+pos; 3 residual gate
// =====================================================================
template <int EPI>
__global__ __launch_bounds__(512, 1) void gemm8(
    const u16* __restrict__ A, int lda, const u16* __restrict__ Bt, int ldb,
    int M, int N, int K, const float* __restrict__ bias,
    float* __restrict__ outF, u16* __restrict__ outB, int ldc,
    const float* __restrict__ aux1, const float* __restrict__ aux2, int gateOff) {
    __shared__ u16 As[3][256 * 64];
    __shared__ u16 Bs[3][128 * 64];

    const int tid = threadIdx.x, w = tid >> 6, l = tid & 63;
    const int wm = w >> 1, wn = w & 1;

    const int nbn = N >> 7;
    const int orig = blockIdx.x;
    const int cpx = gridDim.x >> 3;
    const int wg = (orig & 7) * cpx + (orig >> 3);
    const int bm = wg / nbn, bn = wg - bm * nbn;
    const int row0 = bm << 8, col0 = bn << 7;

    const int NT = K >> 6;

    const int srow = tid >> 3, sslot = tid & 7;
    const int ksl = sslot ^ (srow & 7);
    const u16* gA = A + (size_t)(row0 + srow) * lda + ksl * 8;
    const u16* gB = Bt + (size_t)(col0 + srow) * ldb + ksl * 8;
    const int lOff = srow * 64 + sslot * 8;

    const int fr = l & 15, fg = l >> 4;
    const int arow = wm * 64 + fr;
    const int brow = wn * 64 + fr;

    f32x4 acc[4][4];
#pragma unroll
    for (int m = 0; m < 4; ++m)
#pragma unroll
        for (int n = 0; n < 4; ++n) acc[m][n] = (f32x4){0.f, 0.f, 0.f, 0.f};

    {
        u16* a0 = &As[0][lOff];
        u16* b0 = &Bs[0][lOff];
#pragma unroll
        for (int a = 0; a < 4; ++a) gload16(gA + (size_t)a * 64 * lda, a0 + a * 4096);
#pragma unroll
        for (int b = 0; b < 2; ++b) gload16(gB + (size_t)b * 64 * ldb, b0 + b * 4096);
        if (NT > 1) {
            u16* a1 = &As[1][lOff];
#pragma unroll
            for (int a = 0; a < 3; ++a) gload16(gA + (size_t)a * 64 * lda + 64, a1 + a * 4096);
        }
    }
    if (NT > 1) { asm volatile("s_waitcnt vmcnt(3)" ::: "memory"); }
    else        { asm volatile("s_waitcnt vmcnt(0)" ::: "memory"); }
    __builtin_amdgcn_s_barrier();
    __builtin_amdgcn_sched_barrier(0);

    int q = 0;
    for (int t = 0; t < NT; ++t) {
        const u16* ca = As[q];
        const u16* cb = Bs[q];
        const int q1 = (q == 2) ? 0 : q + 1;
        const int q2 = (q1 == 2) ? 0 : q1 + 1;

        s16x8 af[4][2], bf[4][2];
#pragma unroll
        for (int m = 0; m < 4; ++m) {
            int r = arow + m * 16;
            af[m][0] = *(const s16x8*)(ca + r * 64 + ((fg     ^ (r & 7)) * 8));
            af[m][1] = *(const s16x8*)(ca + r * 64 + (((4 + fg) ^ (r & 7)) * 8));
        }
#pragma unroll
        for (int n = 0; n < 2; ++n) {
            int r = brow + n * 16;
            bf[n][0] = *(const s16x8*)(cb + r * 64 + ((fg     ^ (r & 7)) * 8));
            bf[n][1] = *(const s16x8*)(cb + r * 64 + (((4 + fg) ^ (r & 7)) * 8));
        }
        if (t + 1 < NT) {
            gload16(gA + (size_t)(3 * 64) * lda + (size_t)(t + 1) * 64, &As[q1][lOff] + 3 * 4096);
            gload16(gB + (size_t)(t + 1) * 64, &Bs[q1][lOff]);
            gload16(gB + (size_t)(1 * 64) * ldb + (size_t)(t + 1) * 64, &Bs[q1][lOff] + 4096);
        }
        __builtin_amdgcn_s_barrier();
        __builtin_amdgcn_s_setprio(1);
#pragma unroll
        for (int m = 0; m < 4; ++m)
#pragma unroll
            for (int n = 0; n < 2; ++n) {
                acc[m][n] = mfma16(af[m][0], bf[n][0], acc[m][n]);
                acc[m][n] = mfma16(af[m][1], bf[n][1], acc[m][n]);
            }
        __builtin_amdgcn_s_setprio(0);
        __builtin_amdgcn_s_barrier();
#pragma unroll
        for (int n = 0; n < 2; ++n) {
            int r = brow + (n + 2) * 16;
            bf[n + 2][0] = *(const s16x8*)(cb + r * 64 + ((fg     ^ (r & 7)) * 8));
            bf[n + 2][1] = *(const s16x8*)(cb + r * 64 + (((4 + fg) ^ (r & 7)) * 8));
        }
        if (t + 2 < NT) {
#pragma unroll
            for (int a = 0; a < 3; ++a)
                gload16(gA + (size_t)a * 64 * lda + (size_t)(t + 2) * 64, &As[q2][lOff] + a * 4096);
        }
        __builtin_amdgcn_s_barrier();
        __builtin_amdgcn_s_setprio(1);
#pragma unroll
        for (int m = 0; m < 4; ++m)
#pragma unroll
            for (int n = 2; n < 4; ++n) {
                acc[m][n] = mfma16(af[m][0], bf[n][0], acc[m][n]);
                acc[m][n] = mfma16(af[m][1], bf[n][1], acc[m][n]);
            }
        __builtin_amdgcn_s_setprio(0);
        if (t < NT - 2)       { asm volatile("s_waitcnt vmcnt(3)" ::: "memory"); }
        else if (t == NT - 2) { asm volatile("s_waitcnt vmcnt(0)" ::: "memory"); }
        if (t < NT - 1) {
            __builtin_amdgcn_s_barrier();
            __builtin_amdgcn_sched_barrier(0);
        }
        q = q1;
    }

    const int erow = row0 + wm * 64 + fg * 4;
    const int ecol = col0 + wn * 64 + fr;
#pragma unroll
    for (int m = 0; m < 4; ++m) {
#pragma unroll
        for (int n = 0; n < 4; ++n) {
#pragma unroll
            for (int r = 0; r < 4; ++r) {
                int row = erow + m * 16 + r;
                int col = ecol + n * 16;
                float v = acc[m][n][r];
                if constexpr (EPI == 2) {
                    outF[(size_t)row * ldc + col] = v + bias[col] + aux1[(size_t)(row & 255) * 1024 + col];
                } else {  // EPI == 3
                    outF[(size_t)row * ldc + col] =
                        aux1[(size_t)row * ldc + col] +
                        aux2[(size_t)(row >> 8) * 6144 + gateOff + col] * (v + bias[col]);
                }
            }
        }
    }
}

// ---------- small GEMM (m97-style): final unpatchify only ----------
__global__ __launch_bounds__(256, 2) void gemm_fin(
    const u16* __restrict__ A, int lda, const u16* __restrict__ Bt, int ldb,
    int M, int N, int K, const float* __restrict__ bias, float* outF) {
    __shared__ u16 Asl[128 * 32];
    __shared__ u16 Bsl[128 * 32];
    const int tid = threadIdx.x, w = tid >> 6, l = tid & 63;
    const int row0 = blockIdx.y * 128, col0 = blockIdx.x * 128;
    const int wm = w >> 1, wn = w & 1;

    f32x4 acc[4][4];
#pragma unroll
    for (int m = 0; m < 4; ++m)
#pragma unroll
        for (int n = 0; n < 4; ++n) acc[m][n] = (f32x4){0.f, 0.f, 0.f, 0.f};

    const int rA0 = w * 16 + (l >> 2), rA1 = rA0 + 64;
    const int kc = (l & 3) * 8;
    const u16* a0 = A + (size_t)(row0 + rA0) * lda + kc;
    const u16* a1 = A + (size_t)(row0 + rA1) * lda + kc;
    const u16* b0 = Bt + (size_t)(col0 + rA0) * ldb + kc;
    const u16* b1 = Bt + (size_t)(col0 + rA1) * ldb + kc;
    u16* la0 = &Asl[rA0 * 32 + kc];
    u16* la1 = &Asl[rA1 * 32 + kc];
    u16* lb0 = &Bsl[rA0 * 32 + kc];
    u16* lb1 = &Bsl[rA1 * 32 + kc];

    for (int k0 = 0; k0 < K; k0 += 32) {
        __syncthreads();
        gload16(a0 + k0, la0);
        gload16(a1 + k0, la1);
        gload16(b0 + k0, lb0);
        gload16(b1 + k0, lb1);
        __syncthreads();
        s16x8 af[4], bfr[4];
#pragma unroll
        for (int m = 0; m < 4; ++m)
            af[m] = *(const s16x8*)&Asl[(wm * 64 + m * 16 + (l & 15)) * 32 + (l >> 4) * 8];
#pragma unroll
        for (int n = 0; n < 4; ++n)
            bfr[n] = *(const s16x8*)&Bsl[(wn * 64 + n * 16 + (l & 15)) * 32 + (l >> 4) * 8];
#pragma unroll
        for (int m = 0; m < 4; ++m)
#pragma unroll
            for (int n = 0; n < 4; ++n) acc[m][n] = mfma16(af[m], bfr[n], acc[m][n]);
    }

#pragma unroll
    for (int m = 0; m < 4; ++m) {
#pragma unroll
        for (int n = 0; n < 4; ++n) {
#pragma unroll
            for (int r = 0; r < 4; ++r) {
                int row = row0 + wm * 64 + m * 16 + (l >> 4) * 4 + r;
                int col = col0 + wn * 64 + n * 16 + (l & 15);
                float xg = acc[m][n][r] + bias[col];
                int bb = row >> 8, ll = row & 255, hp = ll >> 4, wp = ll & 15;
                int pp = col >> 6, d = col & 63;
                outF[(size_t)((bb * 64 + d) * 32 + hp * 2 + (pp >> 1)) * 32 + wp * 2 + (pp & 1)] = xg;
            }
        }
    }
}

// ---------- attention: qkv (8192,3072) bf16 -> obuf (8192,1024) bf16 ----------
__global__ __launch_bounds__(256, 2) void attn_kernel(const u16* __restrict__ qkv, u16* __restrict__ obuf) {
    __shared__ u16 Qs[64 * 64];
    __shared__ u16 Ks[256 * 64];    // reused later as P [qrow][ktok]
    __shared__ u16 VTs[64 * 256];
    int qt = blockIdx.x, h = blockIdx.y, b = blockIdx.z;
    int tid = threadIdx.x, w = tid >> 6, l = tid & 63;
    size_t base = (size_t)b * 256 * 3072;

    {
        int r = tid >> 2;
#pragma unroll
        for (int j = 0; j < 2; ++j) {
            int sg = (tid & 3) + j * 4;
            *(s16x8*)&Qs[r * 64 + sg * 8] =
                *(const s16x8*)&qkv[base + (size_t)(qt * 64 + r) * 3072 + h * 64 + sg * 8];
        }
    }
#pragma unroll
    for (int j = 0; j < 8; ++j) {
        int i = tid + j * 256;
        int r = i >> 3, sg = i & 7;
        *(s16x8*)&Ks[r * 64 + sg * 8] =
            *(const s16x8*)&qkv[base + (size_t)r * 3072 + 1024 + h * 64 + sg * 8];
    }
#pragma unroll
    for (int j = 0; j < 8; ++j) {
        int i = tid + j * 256;
        int r = i >> 3, sg = i & 7;
        s16x8 v = *(const s16x8*)&qkv[base + (size_t)r * 3072 + 2048 + h * 64 + sg * 8];
#pragma unroll
        for (int e = 0; e < 8; ++e) VTs[(sg * 8 + e) * 256 + r] = ((const u16*)&v)[e];
    }
    __syncthreads();

    s16x8 aq0 = *(const s16x8*)&Qs[(w * 16 + (l & 15)) * 64 + (l >> 4) * 8];
    s16x8 aq1 = *(const s16x8*)&Qs[(w * 16 + (l & 15)) * 64 + 32 + (l >> 4) * 8];
    f32x4 sf[16];
#pragma unroll
    for (int cf = 0; cf < 16; ++cf) {
        f32x4 a = (f32x4){0.f, 0.f, 0.f, 0.f};
        s16x8 bk0 = *(const s16x8*)&Ks[(cf * 16 + (l & 15)) * 64 + (l >> 4) * 8];
        s16x8 bk1 = *(const s16x8*)&Ks[(cf * 16 + (l & 15)) * 64 + 32 + (l >> 4) * 8];
        a = mfma16(aq0, bk0, a);
        a = mfma16(aq1, bk1, a);
        sf[cf] = a * 0.125f;
    }
    __syncthreads();

#pragma unroll
    for (int r = 0; r < 4; ++r) {
        float m = -1e30f;
#pragma unroll
        for (int cf = 0; cf < 16; ++cf) m = fmaxf(m, sf[cf][r]);
#pragma unroll
        for (int d = 1; d < 16; d <<= 1) m = fmaxf(m, __shfl_xor(m, d));
        float sm = 0.f;
#pragma unroll
        for (int cf = 0; cf < 16; ++cf) { float e = __expf(sf[cf][r] - m); sf[cf][r] = e; sm += e; }
#pragma unroll
        for (int d = 1; d < 16; d <<= 1) sm += __shfl_xor(sm, d);
        float inv = 1.f / sm;
        int rl = w * 16 + (l >> 4) * 4 + r;
#pragma unroll
        for (int cf = 0; cf < 16; ++cf) Ks[rl * 256 + cf * 16 + (l & 15)] = f2b(sf[cf][r] * inv);
    }
    __syncthreads();

    f32x4 oacc[4];
#pragma unroll
    for (int cf = 0; cf < 4; ++cf) oacc[cf] = (f32x4){0.f, 0.f, 0.f, 0.f};
#pragma unroll
    for (int ks = 0; ks < 8; ++ks) {
        s16x8 ap = *(const s16x8*)&Ks[(w * 16 + (l & 15)) * 256 + ks * 32 + (l >> 4) * 8];
#pragma unroll
        for (int cf = 0; cf < 4; ++cf) {
            s16x8 bv = *(const s16x8*)&VTs[(cf * 16 + (l & 15)) * 256 + ks * 32 + (l >> 4) * 8];
            oacc[cf] = mfma16(ap, bv, oacc[cf]);
        }
    }
    size_t orow0 = (size_t)(b * 256 + qt * 64 + w * 16);
#pragma unroll
    for (int cf = 0; cf < 4; ++cf)
#pragma unroll
        for (int r = 0; r < 4; ++r) {
            int rr = (l >> 4) * 4 + r;
            obuf[(orow0 + rr) * 1024 + h * 64 + cf * 16 + (l & 15)] = f2b(oacc[cf][r]);
        }
}

// ---------- host ----------
extern "C" void kernel_launch(void* const* d_in, const int* in_sizes, int n_in,
                              void* d_out, int out_size, void* d_ws, size_t ws_size,
                              hipStream_t stream) {
    (void)in_sizes; (void)n_in; (void)out_size; (void)ws_size;
    const float* x         = (const float*)d_in[0];
    const int*   y         = (const int*)d_in[1];
    const int*   t         = (const int*)d_in[2];
    const float* proj_w    = (const float*)d_in[3];
    const float* proj_b    = (const float*)d_in[4];
    const float* pos_embed = (const float*)d_in[5];
    const float* emb_table = (const float*)d_in[6];
    const float* blk_mod_w = (const float*)d_in[7];
    const float* blk_mod_b = (const float*)d_in[8];
    const float* blk_wq    = (const float*)d_in[9];
    const float* blk_bq    = (const float*)d_in[10];
    const float* blk_wk    = (const float*)d_in[11];
    const float* blk_bk    = (const float*)d_in[12];
    const float* blk_wv    = (const float*)d_in[13];
    const float* blk_bv    = (const float*)d_in[14];
    const float* blk_wo    = (const float*)d_in[15];
    const float* blk_bo    = (const float*)d_in[16];
    const float* blk_f1w   = (const float*)d_in[17];
    const float* blk_f1b   = (const float*)d_in[18];
    const float* blk_f2w   = (const float*)d_in[19];
    const float* blk_f2b   = (const float*)d_in[20];
    const float* fin_mod_w = (const float*)d_in[21];
    const float* fin_mod_b = (const float*)d_in[22];
    const float* fin_out_w = (const float*)d_in[23];
    const float* fin_out_b = (const float*)d_in[24];
    float* out = (float*)d_out;

    char* ws = (char*)d_ws;
    size_t off = 0;
    auto alloc = [&](size_t bytes) -> char* {
        char* p = ws + off;
        off += (bytes + 255) & ~(size_t)255;
        return p;
    };
    float* xc    = (float*)alloc(8192ull * 1024 * 4);
    u16*   hx    = (u16*)alloc(8192ull * 1024 * 2);
    u16*   qkvb  = (u16*)alloc(8192ull * 3072 * 2);
    u16*   obufp = (u16*)alloc(8192ull * 1024 * 2);
    u16*   h1    = (u16*)alloc(8192ull * 4096 * 2);
    u16*   patchA= (u16*)alloc(8192ull * 256 * 2);
    float* cactF = (float*)alloc(32ull * 1024 * 4);
    float* modb  = (float*)alloc(32ull * 6144 * 4);
    float* fmod  = (float*)alloc(32ull * 2048 * 4);
    float* bqkv  = (float*)alloc(12ull * 3072 * 4);
    u16*   projT = (u16*)alloc(1024ull * 256 * 2);
    u16*   foT   = (u16*)alloc(256ull * 1024 * 2);
    u16*   qkvT  = (u16*)alloc(3072ull * 1024 * 2);
    u16*   woT   = (u16*)alloc(1024ull * 1024 * 2);
    u16*   f1T   = (u16*)alloc(4096ull * 1024 * 2);
    u16*   f2T   = (u16*)alloc(1024ull * 4096 * 2);

    patchify_kernel<<<8192, 256, 0, stream>>>(x, patchA);
    cact_kernel<<<32, 256, 0, stream>>>(t, y, emb_table, cactF);
    bcat_kernel<<<dim3(12, 3), 256, 0, stream>>>(blk_bq, blk_bk, blk_bv, bqkv);
    transpose_cvt64k<<<dim3(16, 4), 256, 0, stream>>>(proj_w, projT, 256, 1024);
    transpose_cvt64k<<<dim3(4, 16), 256, 0, stream>>>(fin_out_w, foT, 1024, 256);
    mod32_kernel<<<32, 256, 0, stream>>>(cactF, fin_mod_w, fin_mod_b, fmod, 2048);

    // tok = patchA @ proj_w + b + pos  -> xc f32   (M=8192,N=1024,K=256)
    gemm8<2><<<256, 512, 0, stream>>>(patchA, 256, projT, 256, 8192, 1024, 256,
                                      proj_b, xc, nullptr, 1024, pos_embed, nullptr, 0);

    for (int i = 0; i < 12; ++i) {
        transpose_layer<<<3072, 256, 0, stream>>>(
            blk_wq + (size_t)i * 1024 * 1024, blk_wk + (size_t)i * 1024 * 1024,
            blk_wv + (size_t)i * 1024 * 1024, blk_wo + (size_t)i * 1024 * 1024,
            blk_f1w + (size_t)i * 1024 * 4096, blk_f2w + (size_t)i * 4096 * 1024,
            qkvT, woT, f1T, f2T);

        // mod = c_act @ mod_w + mod_b   (32 x 6144), pure fp32
        mod32_kernel<<<96, 256, 0, stream>>>(cactF, blk_mod_w + (size_t)i * 1024 * 6144,
                                             blk_mod_b + (size_t)i * 6144, modb, 6144);
        // hx = ln(xc)*(1+sc_a)+sh_a
        ln_mod_kernel<<<8192, 256, 0, stream>>>(xc, modb, 6144, 0, 1024, hx);
        // qkv = hx @ [wq|wk|wv] + biases  -> bf16
        gemm256<1><<<384, 512, 0, stream>>>(hx, 1024, qkvT, 1024, 8192, 3072, 1024,
                                            bqkv + (size_t)i * 3072, qkvb, 3072);
        attn_kernel<<<dim3(4, 16, 32), 256, 0, stream>>>(qkvb, obufp);
        // xc += g_a * (o @ wo + bo)
        gemm8<3><<<256, 512, 0, stream>>>(obufp, 1024, woT, 1024, 8192, 1024, 1024,
                                          blk_bo + (size_t)i * 1024, xc, nullptr, 1024,
                                          xc, modb, 2048);
        // hx = ln(xc)*(1+sc_m)+sh_m
        ln_mod_kernel<<<8192, 256, 0, stream>>>(xc, modb, 6144, 3072, 4096, hx);
        // h1 = gelu(hx @ f1 + b1)
        gemm256<4><<<512, 512, 0, stream>>>(hx, 1024, f1T, 1024, 8192, 4096, 1024,
                                            blk_f1b + (size_t)i * 4096, h1, 4096);
        // xc += g_m * (h1 @ f2 + b2)
        gemm8<3><<<256, 512, 0, stream>>>(h1, 4096, f2T, 4096, 8192, 1024, 4096,
                                          blk_f2b + (size_t)i * 1024, xc, nullptr, 1024,
                                          xc, modb, 5120);
    }
    // final: hx = ln(xc)*(1+sc)+sh ; out = unpatchify(hx @ fin_out_w + b)
    ln_mod_kernel<<<8192, 256, 0, stream>>>(xc, fmod, 2048, 0, 1024, hx);
    gemm_fin<<<dim3(2, 64), 256, 0, stream>>>(hx, 1024, foT, 1024, 8192, 256, 1024,
                                              fin_out_b, out);
}

// Round 4
// 6092.250 us; speedup vs baseline: 1.0110x; 1.0110x over previous
//
#include <hip/hip_runtime.h>
#include <hip/hip_bf16.h>
#include <math.h>

typedef short s16x8 __attribute__((ext_vector_type(8)));
typedef float f32x4 __attribute__((ext_vector_type(4)));
typedef unsigned short u16;

#define BAR() __builtin_amdgcn_s_barrier()
#define PRIO1() __builtin_amdgcn_s_setprio(1)
#define PRIO0() __builtin_amdgcn_s_setprio(0)
#define VMCNT6() asm volatile("s_waitcnt vmcnt(6)" ::: "memory")
#define VMCNT0() asm volatile("s_waitcnt vmcnt(0)" ::: "memory")

// ---------- helpers ----------
__device__ __forceinline__ u16 f2b(float f) {
    unsigned u = __builtin_bit_cast(unsigned, f);
    u += 0x7fffu + ((u >> 16) & 1u);           // round-to-nearest-even
    return (u16)(u >> 16);
}
__device__ __forceinline__ f32x4 mfma16(s16x8 a, s16x8 b, f32x4 c) {
    return __builtin_amdgcn_mfma_f32_16x16x32_bf16(a, b, c, 0, 0, 0);
}
__device__ __forceinline__ void gload16(const void* g, void* l) {
    __builtin_amdgcn_global_load_lds((const __attribute__((address_space(1))) unsigned*)g,
                                     (__attribute__((address_space(3))) unsigned*)l, 16, 0, 0);
}

// ---------- patchify: x (32,64,32,32) f32 -> patchA (8192,256) bf16 ----------
__global__ __launch_bounds__(256) void patchify_kernel(const float* __restrict__ x, u16* __restrict__ out) {
    int idx = blockIdx.x * 256 + threadIdx.x;
    int row = idx >> 8, col = idx & 255;
    int b = row >> 8, ll = row & 255, hp = ll >> 4, wp = ll & 15;
    int pp = col >> 6, d = col & 63;
    out[idx] = f2b(x[(size_t)((b * 64 + d) * 32 + hp * 2 + (pp >> 1)) * 32 + wp * 2 + (pp & 1)]);
}

// ---------- c_act = silu(timestep_emb + emb_table[y]) -> f32 (32,1024) ----------
__global__ __launch_bounds__(256) void cact_kernel(const int* __restrict__ t, const int* __restrict__ y,
                                                   const float* __restrict__ emb, float* __restrict__ cactF) {
    int b = blockIdx.x, tid = threadIdx.x;
    float tv = (float)t[b];
    int yb = y[b];
#pragma unroll
    for (int j = 0; j < 4; ++j) {
        int c = tid * 4 + j;
        int f = (c < 512) ? c : c - 512;
        float freq = __expf(-9.210340371976184f * (float)f * (1.f / 512.f));
        float ang = tv * freq;
        float v = (c < 512) ? cosf(ang) : sinf(ang);
        v += emb[(size_t)yb * 1024 + c];
        v = v / (1.f + __expf(-v));   // silu
        cactF[b * 1024 + c] = v;
    }
}

// ---------- concat q/k/v biases for all 12 layers -> (12,3072) f32 ----------
__global__ __launch_bounds__(256) void bcat_kernel(const float* __restrict__ bq, const float* __restrict__ bk,
                                                   const float* __restrict__ bv, float* __restrict__ out) {
    int lyr = blockIdx.x, j = blockIdx.y, tid = threadIdx.x;
    const float* src = (j == 0) ? bq : ((j == 1) ? bk : bv);
    float4 v = ((const float4*)(src + (size_t)lyr * 1024))[tid];
    ((float4*)(out + (size_t)lyr * 3072 + j * 1024))[tid] = v;
}

// ---------- mod32: out(32,N) = cactF(32,1024) @ W(1024,N) + bias, all f32 ----------
__global__ __launch_bounds__(256) void mod32_kernel(const float* __restrict__ cactF, const float* __restrict__ W,
                                                    const float* __restrict__ bias, float* __restrict__ out, int N) {
    __shared__ float cs[32 * 256];
    __shared__ float red[4 * 32 * 64];
    int tid = threadIdx.x, lane = tid & 63, kg = tid >> 6;
    int n = blockIdx.x * 64 + lane;
    float acc[32];
#pragma unroll
    for (int r = 0; r < 32; ++r) acc[r] = 0.f;
    for (int ch = 0; ch < 4; ++ch) {
        __syncthreads();
#pragma unroll
        for (int j = 0; j < 8; ++j) {
            int idx = tid * 4 + j * 1024;
            float4 v = *(const float4*)&cactF[(size_t)(idx >> 8) * 1024 + ch * 256 + (idx & 255)];
            *(float4*)&cs[idx] = v;
        }
        __syncthreads();
        const float* Wp = W + (size_t)(ch * 256 + kg * 64) * N + n;
        for (int kk = 0; kk < 64; kk += 4) {
            float w0 = Wp[(size_t)(kk + 0) * N];
            float w1 = Wp[(size_t)(kk + 1) * N];
            float w2 = Wp[(size_t)(kk + 2) * N];
            float w3 = Wp[(size_t)(kk + 3) * N];
            int kb = kg * 64 + kk;
#pragma unroll
            for (int r = 0; r < 32; ++r) {
                float4 cv = *(const float4*)&cs[r * 256 + kb];
                acc[r] += cv.x * w0 + cv.y * w1 + cv.z * w2 + cv.w * w3;
            }
        }
    }
#pragma unroll
    for (int r = 0; r < 32; ++r) red[(kg * 32 + r) * 64 + lane] = acc[r];
    __syncthreads();
    int r = tid >> 3, j0 = (tid & 7) * 8;
#pragma unroll
    for (int jj = 0; jj < 8; ++jj) {
        int nn = j0 + jj;
        float s = red[(0 * 32 + r) * 64 + nn] + red[(1 * 32 + r) * 64 + nn] +
                  red[(2 * 32 + r) * 64 + nn] + red[(3 * 32 + r) * 64 + nn];
        out[(size_t)r * N + blockIdx.x * 64 + nn] = s + bias[blockIdx.x * 64 + nn];
    }
}

// ---------- 64x64 transpose + f32->bf16 convert body ----------
__device__ __forceinline__ void tpose_body(float (*tile)[65], const float* __restrict__ in,
                                           u16* __restrict__ out, int R, int C, int r0, int c0, int tid) {
    int rr = tid >> 4, cc = (tid & 15) * 4;
#pragma unroll
    for (int j = 0; j < 4; ++j) {
        float4 v = *(const float4*)&in[(size_t)(r0 + j * 16 + rr) * C + c0 + cc];
        tile[j * 16 + rr][cc]     = v.x;
        tile[j * 16 + rr][cc + 1] = v.y;
        tile[j * 16 + rr][cc + 2] = v.z;
        tile[j * 16 + rr][cc + 3] = v.w;
    }
    __syncthreads();
    int oc = tid >> 3, r8 = (tid & 7) * 8;
#pragma unroll
    for (int j = 0; j < 2; ++j) {
        int ocl = j * 32 + oc;
        s16x8 vv;
#pragma unroll
        for (int e = 0; e < 8; ++e) vv[e] = (short)f2b(tile[r8 + e][ocl]);
        *(s16x8*)&out[(size_t)(c0 + ocl) * R + r0 + r8] = vv;
    }
}

__global__ __launch_bounds__(256) void transpose_cvt64k(const float* __restrict__ in, u16* __restrict__ out,
                                                        int R, int C) {
    __shared__ float tile[64][65];
    tpose_body(tile, in, out, R, C, blockIdx.y * 64, blockIdx.x * 64, threadIdx.x);
}

// ---------- one layer's attention/MLP weights, transposed+converted ----------
__global__ __launch_bounds__(256) void transpose_layer(
    const float* __restrict__ wq, const float* __restrict__ wk,
    const float* __restrict__ wv, const float* __restrict__ wo, const float* __restrict__ f1,
    const float* __restrict__ f2,
    u16* __restrict__ qkvT, u16* __restrict__ woT, u16* __restrict__ f1T, u16* __restrict__ f2T) {
    __shared__ float tile[64][65];
    int bid = blockIdx.x, tid = threadIdx.x;
    const float* src; u16* dst; int R, C, tloc;
    if (bid < 256)       { src = wq; dst = qkvT;               R = 1024; C = 1024; tloc = bid; }
    else if (bid < 512)  { src = wk; dst = qkvT + 1024 * 1024; R = 1024; C = 1024; tloc = bid - 256; }
    else if (bid < 768)  { src = wv; dst = qkvT + 2048 * 1024; R = 1024; C = 1024; tloc = bid - 512; }
    else if (bid < 1024) { src = wo; dst = woT;                R = 1024; C = 1024; tloc = bid - 768; }
    else if (bid < 2048) { src = f1; dst = f1T;                R = 1024; C = 4096; tloc = bid - 1024; }
    else                 { src = f2; dst = f2T;                R = 4096; C = 1024; tloc = bid - 2048; }
    int tx = C >> 6;
    int ty = tloc / tx, txi = tloc - ty * tx;
    tpose_body(tile, src, dst, R, C, ty * 64, txi * 64, tid);
}

// ---------- LayerNorm + modulate: hx = ln(x)*(1+sc)+sh -> bf16 ----------
__global__ __launch_bounds__(256) void ln_mod_kernel(const float* __restrict__ x, const float* __restrict__ modv,
                                                     int mod_ld, int sh_off, int sc_off, u16* __restrict__ out) {
    int row = blockIdx.x, tid = threadIdx.x, b = row >> 8;
    float4 xv = ((const float4*)(x + (size_t)row * 1024))[tid];
    float s = xv.x + xv.y + xv.z + xv.w;
    float s2 = xv.x * xv.x + xv.y * xv.y + xv.z * xv.z + xv.w * xv.w;
#pragma unroll
    for (int d = 1; d < 64; d <<= 1) { s += __shfl_xor(s, d); s2 += __shfl_xor(s2, d); }
    __shared__ float red[8];
    int w = tid >> 6;
    if ((tid & 63) == 0) { red[w] = s; red[4 + w] = s2; }
    __syncthreads();
    s = red[0] + red[1] + red[2] + red[3];
    s2 = red[4] + red[5] + red[6] + red[7];
    float mu = s * (1.f / 1024.f);
    float rs = rsqrtf(s2 * (1.f / 1024.f) - mu * mu + 1e-5f);
    const float* shp = modv + (size_t)b * mod_ld + sh_off;
    const float* scp = modv + (size_t)b * mod_ld + sc_off;
    float4 sh4 = ((const float4*)shp)[tid];
    float4 sc4 = ((const float4*)scp)[tid];
    u16 o0 = f2b((xv.x - mu) * rs * (1.f + sc4.x) + sh4.x);
    u16 o1 = f2b((xv.y - mu) * rs * (1.f + sc4.y) + sh4.y);
    u16 o2 = f2b((xv.z - mu) * rs * (1.f + sc4.z) + sh4.z);
    u16 o3 = f2b((xv.w - mu) * rs * (1.f + sc4.w) + sh4.w);
    unsigned long long pk = (unsigned long long)o0 | ((unsigned long long)o1 << 16) |
                            ((unsigned long long)o2 << 32) | ((unsigned long long)o3 << 48);
    *(unsigned long long*)&out[(size_t)row * 1024 + tid * 4] = pk;
}

// =====================================================================
// gemm256_8ph: m201-style 8-phase 256x256 GEMM, BK=64, 512 thr (2Mx4N
// waves, 128x64/wave), LDS 2dbuf x 2half x [128][64] x {A,B} = 128 KB.
// Counted vmcnt(6) at phases 4/8; slot swizzle s ^= (row&7) both sides.
// C = A(MxK,bf16) @ Bt(NxK,bf16)^T. M%256==0, N%256==0, K%128==0, grid%8==0.
// EPI 1: bf16+bias; EPI 4: gelu bf16
// =====================================================================
template <int EPI>
__global__ __launch_bounds__(512, 2) void gemm256_8ph(
    const u16* __restrict__ A, int lda, const u16* __restrict__ Bt, int ldb,
    int M, int N, int K, const float* __restrict__ bias, u16* __restrict__ outB, int ldc) {
    __shared__ u16 As[2][2][128 * 64];
    __shared__ u16 Bs[2][2][128 * 64];

    const int tid = threadIdx.x, w = tid >> 6, l = tid & 63;
    const int wm = w >> 2, wn = w & 3;        // 2M x 4N
    const int fr = l & 15, fg = l >> 4;

    const int nbn = N >> 8;
    const int orig = blockIdx.x;
    const int cpx = gridDim.x >> 3;
    const int wg = (orig & 7) * cpx + (orig >> 3);   // XCD-chunked swizzle (grid%8==0)
    const int bm = wg / nbn, bn = wg - bm * nbn;
    const int row0 = bm << 8, col0 = bn << 8;
    const int NT = K >> 6;

    // staging coords
    const int srow = tid >> 3, slot = tid & 7;
    const int gsl = slot ^ (srow & 7);               // pre-swizzled global slot

    auto stA = [&](int d, int h, int tt) {
        const u16* src = A + (size_t)(row0 + h * 128 + srow) * lda + (size_t)tt * 64 + gsl * 8;
        u16* dst = &As[d][h][tid * 8];
        gload16(src, dst);
        gload16(src + (size_t)64 * lda, dst + 64 * 64);
    };
    auto stB = [&](int d, int h, int tt) {
        const u16* src = Bt + (size_t)(col0 + h * 128 + srow) * ldb + (size_t)tt * 64 + gsl * 8;
        u16* dst = &Bs[d][h][tid * 8];
        gload16(src, dst);
        gload16(src + (size_t)64 * ldb, dst + 64 * 64);
    };

    const int swz0 = (fg ^ (fr & 7)) * 8;            // k-half 0 slot (bytes/2)
    const int swz1 = ((fg + 4) ^ (fr & 7)) * 8;      // k-half 1 slot
    auto ldA = [&](int d, int mh, s16x8 (&out)[4][2]) {
#pragma unroll
        for (int m = 0; m < 4; ++m) {
            const u16* p = &As[d][wm][(mh * 64 + m * 16 + fr) * 64];
            out[m][0] = *(const s16x8*)(p + swz0);
            out[m][1] = *(const s16x8*)(p + swz1);
        }
    };
    auto ldB = [&](int d, int nh, s16x8 (&out)[2][2]) {
#pragma unroll
        for (int n = 0; n < 2; ++n) {
            const u16* p = &Bs[d][wn >> 1][((wn & 1) * 64 + nh * 32 + n * 16 + fr) * 64];
            out[n][0] = *(const s16x8*)(p + swz0);
            out[n][1] = *(const s16x8*)(p + swz1);
        }
    };

    f32x4 acc[8][4];
#pragma unroll
    for (int m = 0; m < 8; ++m)
#pragma unroll
        for (int n = 0; n < 4; ++n) acc[m][n] = (f32x4){0.f, 0.f, 0.f, 0.f};

    auto MQ = [&](int mh, int nh, s16x8 (&Aa)[4][2], s16x8 (&Bb)[2][2]) {
#pragma unroll
        for (int m = 0; m < 4; ++m)
#pragma unroll
            for (int n = 0; n < 2; ++n) {
                f32x4 c = acc[mh * 4 + m][nh * 2 + n];
                c = mfma16(Aa[m][0], Bb[n][0], c);
                c = mfma16(Aa[m][1], Bb[n][1], c);
                acc[mh * 4 + m][nh * 2 + n] = c;
            }
    };

    // prologue: tile0 full -> dbuf0; tile1 A0,A1,B0 -> dbuf1 (14 loads)
    stA(0, 0, 0); stA(0, 1, 0); stB(0, 0, 0); stB(0, 1, 0);
    stA(1, 0, 1); stA(1, 1, 1); stB(1, 0, 1);
    VMCNT6();                                  // tile0 resident; 3 half-tiles in flight
    BAR();
    __builtin_amdgcn_sched_barrier(0);

    for (int t = 0; t < NT; t += 2) {
        const bool more = (t + 2 < NT);        // NT even => t+3<NT iff t+2<NT
        s16x8 Aa[4][2], Ab[4][2], B0[2][2], B1[2][2];
        // ---- ph0: A(mh0)+B(nh0) reads; stage (t+1).B1 -> dbuf1 ----
        ldA(0, 0, Aa); ldB(0, 0, B0);
        stB(1, 1, t + 1);
        BAR(); PRIO1(); MQ(0, 0, Aa, B0); PRIO0(); BAR();
        // ---- ph1: B(nh1) reads ----
        ldB(0, 1, B1);
        BAR(); PRIO1(); MQ(0, 1, Aa, B1); PRIO0(); BAR();
        // ---- ph2: A(mh1) reads; stage (t+2).B0 -> dbuf0 ----
        ldA(0, 1, Ab);
        if (more) stB(0, 0, t + 2);
        BAR(); PRIO1(); MQ(1, 1, Ab, B1); PRIO0(); BAR();
        // ---- ph3: stage (t+2).B1,(t+2).A0 -> dbuf0; vmcnt gate for dbuf1 ----
        if (more) { stB(0, 1, t + 2); stA(0, 0, t + 2); }
        BAR(); PRIO1(); MQ(1, 0, Ab, B0); PRIO0();
        if (more) { VMCNT6(); } else { VMCNT0(); }
        BAR();
        // ---- ph4: tile t+1 (dbuf1): A(mh0)+B(nh0); stage (t+2).A1 ----
        ldA(1, 0, Aa); ldB(1, 0, B0);
        if (more) stA(0, 1, t + 2);
        BAR(); PRIO1(); MQ(0, 0, Aa, B0); PRIO0(); BAR();
        // ---- ph5 ----
        ldB(1, 1, B1);
        BAR(); PRIO1(); MQ(0, 1, Aa, B1); PRIO0(); BAR();
        // ---- ph6: stage (t+3).B0 -> dbuf1 ----
        ldA(1, 1, Ab);
        if (more) stB(1, 0, t + 3);
        BAR(); PRIO1(); MQ(1, 1, Ab, B1); PRIO0(); BAR();
        // ---- ph7: stage (t+3).A0,(t+3).A1 -> dbuf1; vmcnt gate ----
        if (more) { stA(1, 0, t + 3); stA(1, 1, t + 3); }
        BAR(); PRIO1(); MQ(1, 0, Ab, B0); PRIO0();
        if (more) {
            VMCNT6();
            BAR();
            __builtin_amdgcn_sched_barrier(0);
        }
    }

    // epilogue
#pragma unroll
    for (int m = 0; m < 8; ++m) {
#pragma unroll
        for (int n = 0; n < 4; ++n) {
#pragma unroll
            for (int r = 0; r < 4; ++r) {
                int row = row0 + wm * 128 + m * 16 + fg * 4 + r;
                int col = col0 + wn * 64 + n * 16 + fr;
                float v = acc[m][n][r] + bias[col];
                if constexpr (EPI == 1) {
                    outB[(size_t)row * ldc + col] = f2b(v);
                } else {  // EPI == 4: exact gelu
                    outB[(size_t)row * ldc + col] = f2b(0.5f * v * (1.f + erff(v * 0.70710678118654752f)));
                }
            }
        }
    }
}

// =====================================================================
// gemm8: pipelined GEMM, BM=256 x BN=128, BK=64, 512 thr (8 waves 4x2),
// 3 LDS buffers, counted vmcnt, granule swizzle g ^= r&7.
// EPI: 2 f32+bias+pos; 3 residual gate
// =====================================================================
template <int EPI>
__global__ __launch_bounds__(512, 1) void gemm8(
    const u16* __restrict__ A, int lda, const u16* __restrict__ Bt, int ldb,
    int M, int N, int K, const float* __restrict__ bias,
    float* __restrict__ outF, u16* __restrict__ outB, int ldc,
    const float* __restrict__ aux1, const float* __restrict__ aux2, int gateOff) {
    __shared__ u16 As[3][256 * 64];
    __shared__ u16 Bs[3][128 * 64];

    const int tid = threadIdx.x, w = tid >> 6, l = tid & 63;
    const int wm = w >> 1, wn = w & 1;

    const int nbn = N >> 7;
    const int orig = blockIdx.x;
    const int cpx = gridDim.x >> 3;
    const int wg = (orig & 7) * cpx + (orig >> 3);
    const int bm = wg / nbn, bn = wg - bm * nbn;
    const int row0 = bm << 8, col0 = bn << 7;

    const int NT = K >> 6;

    const int srow = tid >> 3, sslot = tid & 7;
    const int ksl = sslot ^ (srow & 7);
    const u16* gA = A + (size_t)(row0 + srow) * lda + ksl * 8;
    const u16* gB = Bt + (size_t)(col0 + srow) * ldb + ksl * 8;
    const int lOff = srow * 64 + sslot * 8;

    const int fr = l & 15, fg = l >> 4;
    const int arow = wm * 64 + fr;
    const int brow = wn * 64 + fr;

    f32x4 acc[4][4];
#pragma unroll
    for (int m = 0; m < 4; ++m)
#pragma unroll
        for (int n = 0; n < 4; ++n) acc[m][n] = (f32x4){0.f, 0.f, 0.f, 0.f};

    {
        u16* a0 = &As[0][lOff];
        u16* b0 = &Bs[0][lOff];
#pragma unroll
        for (int a = 0; a < 4; ++a) gload16(gA + (size_t)a * 64 * lda, a0 + a * 4096);
#pragma unroll
        for (int b = 0; b < 2; ++b) gload16(gB + (size_t)b * 64 * ldb, b0 + b * 4096);
        if (NT > 1) {
            u16* a1 = &As[1][lOff];
#pragma unroll
            for (int a = 0; a < 3; ++a) gload16(gA + (size_t)a * 64 * lda + 64, a1 + a * 4096);
        }
    }
    if (NT > 1) { asm volatile("s_waitcnt vmcnt(3)" ::: "memory"); }
    else        { VMCNT0(); }
    BAR();
    __builtin_amdgcn_sched_barrier(0);

    int q = 0;
    for (int t = 0; t < NT; ++t) {
        const u16* ca = As[q];
        const u16* cb = Bs[q];
        const int q1 = (q == 2) ? 0 : q + 1;
        const int q2 = (q1 == 2) ? 0 : q1 + 1;

        s16x8 af[4][2], bf[4][2];
#pragma unroll
        for (int m = 0; m < 4; ++m) {
            int r = arow + m * 16;
            af[m][0] = *(const s16x8*)(ca + r * 64 + ((fg     ^ (r & 7)) * 8));
            af[m][1] = *(const s16x8*)(ca + r * 64 + (((4 + fg) ^ (r & 7)) * 8));
        }
#pragma unroll
        for (int n = 0; n < 2; ++n) {
            int r = brow + n * 16;
            bf[n][0] = *(const s16x8*)(cb + r * 64 + ((fg     ^ (r & 7)) * 8));
            bf[n][1] = *(const s16x8*)(cb + r * 64 + (((4 + fg) ^ (r & 7)) * 8));
        }
        if (t + 1 < NT) {
            gload16(gA + (size_t)(3 * 64) * lda + (size_t)(t + 1) * 64, &As[q1][lOff] + 3 * 4096);
            gload16(gB + (size_t)(t + 1) * 64, &Bs[q1][lOff]);
            gload16(gB + (size_t)(1 * 64) * ldb + (size_t)(t + 1) * 64, &Bs[q1][lOff] + 4096);
        }
        BAR(); PRIO1();
#pragma unroll
        for (int m = 0; m < 4; ++m)
#pragma unroll
            for (int n = 0; n < 2; ++n) {
                acc[m][n] = mfma16(af[m][0], bf[n][0], acc[m][n]);
                acc[m][n] = mfma16(af[m][1], bf[n][1], acc[m][n]);
            }
        PRIO0(); BAR();
#pragma unroll
        for (int n = 0; n < 2; ++n) {
            int r = brow + (n + 2) * 16;
            bf[n + 2][0] = *(const s16x8*)(cb + r * 64 + ((fg     ^ (r & 7)) * 8));
            bf[n + 2][1] = *(const s16x8*)(cb + r * 64 + (((4 + fg) ^ (r & 7)) * 8));
        }
        if (t + 2 < NT) {
#pragma unroll
            for (int a = 0; a < 3; ++a)
                gload16(gA + (size_t)a * 64 * lda + (size_t)(t + 2) * 64, &As[q2][lOff] + a * 4096);
        }
        BAR(); PRIO1();
#pragma unroll
        for (int m = 0; m < 4; ++m)
#pragma unroll
            for (int n = 2; n < 4; ++n) {
                acc[m][n] = mfma16(af[m][0], bf[n][0], acc[m][n]);
                acc[m][n] = mfma16(af[m][1], bf[n][1], acc[m][n]);
            }
        PRIO0();
        if (t < NT - 2)       { asm volatile("s_waitcnt vmcnt(3)" ::: "memory"); }
        else if (t == NT - 2) { VMCNT0(); }
        if (t < NT - 1) {
            BAR();
            __builtin_amdgcn_sched_barrier(0);
        }
        q = q1;
    }

    const int erow = row0 + wm * 64 + fg * 4;
    const int ecol = col0 + wn * 64 + fr;
#pragma unroll
    for (int m = 0; m < 4; ++m) {
#pragma unroll
        for (int n = 0; n < 4; ++n) {
#pragma unroll
            for (int r = 0; r < 4; ++r) {
                int row = erow + m * 16 + r;
                int col = ecol + n * 16;
                float v = acc[m][n][r];
                if constexpr (EPI == 2) {
                    outF[(size_t)row * ldc + col] = v + bias[col] + aux1[(size_t)(row & 255) * 1024 + col];
                } else {  // EPI == 3
                    outF[(size_t)row * ldc + col] =
                        aux1[(size_t)row * ldc + col] +
                        aux2[(size_t)(row >> 8) * 6144 + gateOff + col] * (v + bias[col]);
                }
            }
        }
    }
}

// ---------- small GEMM (m97-style): final unpatchify only ----------
__global__ __launch_bounds__(256, 2) void gemm_fin(
    const u16* __restrict__ A, int lda, const u16* __restrict__ Bt, int ldb,
    int M, int N, int K, const float* __restrict__ bias, float* outF) {
    __shared__ u16 Asl[128 * 32];
    __shared__ u16 Bsl[128 * 32];
    const int tid = threadIdx.x, w = tid >> 6, l = tid & 63;
    const int row0 = blockIdx.y * 128, col0 = blockIdx.x * 128;
    const int wm = w >> 1, wn = w & 1;

    f32x4 acc[4][4];
#pragma unroll
    for (int m = 0; m < 4; ++m)
#pragma unroll
        for (int n = 0; n < 4; ++n) acc[m][n] = (f32x4){0.f, 0.f, 0.f, 0.f};

    const int rA0 = w * 16 + (l >> 2), rA1 = rA0 + 64;
    const int kc = (l & 3) * 8;
    const u16* a0 = A + (size_t)(row0 + rA0) * lda + kc;
    const u16* a1 = A + (size_t)(row0 + rA1) * lda + kc;
    const u16* b0 = Bt + (size_t)(col0 + rA0) * ldb + kc;
    const u16* b1 = Bt + (size_t)(col0 + rA1) * ldb + kc;
    u16* la0 = &Asl[rA0 * 32 + kc];
    u16* la1 = &Asl[rA1 * 32 + kc];
    u16* lb0 = &Bsl[rA0 * 32 + kc];
    u16* lb1 = &Bsl[rA1 * 32 + kc];

    for (int k0 = 0; k0 < K; k0 += 32) {
        __syncthreads();
        gload16(a0 + k0, la0);
        gload16(a1 + k0, la1);
        gload16(b0 + k0, lb0);
        gload16(b1 + k0, lb1);
        __syncthreads();
        s16x8 af[4], bfr[4];
#pragma unroll
        for (int m = 0; m < 4; ++m)
            af[m] = *(const s16x8*)&Asl[(wm * 64 + m * 16 + (l & 15)) * 32 + (l >> 4) * 8];
#pragma unroll
        for (int n = 0; n < 4; ++n)
            bfr[n] = *(const s16x8*)&Bsl[(wn * 64 + n * 16 + (l & 15)) * 32 + (l >> 4) * 8];
#pragma unroll
        for (int m = 0; m < 4; ++m)
#pragma unroll
            for (int n = 0; n < 4; ++n) acc[m][n] = mfma16(af[m], bfr[n], acc[m][n]);
    }

#pragma unroll
    for (int m = 0; m < 4; ++m) {
#pragma unroll
        for (int n = 0; n < 4; ++n) {
#pragma unroll
            for (int r = 0; r < 4; ++r) {
                int row = row0 + wm * 64 + m * 16 + (l >> 4) * 4 + r;
                int col = col0 + wn * 64 + n * 16 + (l & 15);
                float xg = acc[m][n][r] + bias[col];
                int bb = row >> 8, ll = row & 255, hp = ll >> 4, wp = ll & 15;
                int pp = col >> 6, d = col & 63;
                outF[(size_t)((bb * 64 + d) * 32 + hp * 2 + (pp >> 1)) * 32 + wp * 2 + (pp & 1)] = xg;
            }
        }
    }
}

// ---------- attention: qkv (8192,3072) bf16 -> obuf (8192,1024) bf16 ----------
__global__ __launch_bounds__(256, 2) void attn_kernel(const u16* __restrict__ qkv, u16* __restrict__ obuf) {
    __shared__ u16 Qs[64 * 64];
    __shared__ u16 Ks[256 * 64];    // reused later as P [qrow][ktok]
    __shared__ u16 VTs[64 * 256];
    int qt = blockIdx.x, h = blockIdx.y, b = blockIdx.z;
    int tid = threadIdx.x, w = tid >> 6, l = tid & 63;
    size_t base = (size_t)b * 256 * 3072;

    {
        int r = tid >> 2;
#pragma unroll
        for (int j = 0; j < 2; ++j) {
            int sg = (tid & 3) + j * 4;
            *(s16x8*)&Qs[r * 64 + sg * 8] =
                *(const s16x8*)&qkv[base + (size_t)(qt * 64 + r) * 3072 + h * 64 + sg * 8];
        }
    }
#pragma unroll
    for (int j = 0; j < 8; ++j) {
        int i = tid + j * 256;
        int r = i >> 3, sg = i & 7;
        *(s16x8*)&Ks[r * 64 + sg * 8] =
            *(const s16x8*)&qkv[base + (size_t)r * 3072 + 1024 + h * 64 + sg * 8];
    }
#pragma unroll
    for (int j = 0; j < 8; ++j) {
        int i = tid + j * 256;
        int r = i >> 3, sg = i & 7;
        s16x8 v = *(const s16x8*)&qkv[base + (size_t)r * 3072 + 2048 + h * 64 + sg * 8];
#pragma unroll
        for (int e = 0; e < 8; ++e) VTs[(sg * 8 + e) * 256 + r] = ((const u16*)&v)[e];
    }
    __syncthreads();

    s16x8 aq0 = *(const s16x8*)&Qs[(w * 16 + (l & 15)) * 64 + (l >> 4) * 8];
    s16x8 aq1 = *(const s16x8*)&Qs[(w * 16 + (l & 15)) * 64 + 32 + (l >> 4) * 8];
    f32x4 sf[16];
#pragma unroll
    for (int cf = 0; cf < 16; ++cf) {
        f32x4 a = (f32x4){0.f, 0.f, 0.f, 0.f};
        s16x8 bk0 = *(const s16x8*)&Ks[(cf * 16 + (l & 15)) * 64 + (l >> 4) * 8];
        s16x8 bk1 = *(const s16x8*)&Ks[(cf * 16 + (l & 15)) * 64 + 32 + (l >> 4) * 8];
        a = mfma16(aq0, bk0, a);
        a = mfma16(aq1, bk1, a);
        sf[cf] = a * 0.125f;
    }
    __syncthreads();

#pragma unroll
    for (int r = 0; r < 4; ++r) {
        float m = -1e30f;
#pragma unroll
        for (int cf = 0; cf < 16; ++cf) m = fmaxf(m, sf[cf][r]);
#pragma unroll
        for (int d = 1; d < 16; d <<= 1) m = fmaxf(m, __shfl_xor(m, d));
        float sm = 0.f;
#pragma unroll
        for (int cf = 0; cf < 16; ++cf) { float e = __expf(sf[cf][r] - m); sf[cf][r] = e; sm += e; }
#pragma unroll
        for (int d = 1; d < 16; d <<= 1) sm += __shfl_xor(sm, d);
        float inv = 1.f / sm;
        int rl = w * 16 + (l >> 4) * 4 + r;
#pragma unroll
        for (int cf = 0; cf < 16; ++cf) Ks[rl * 256 + cf * 16 + (l & 15)] = f2b(sf[cf][r] * inv);
    }
    __syncthreads();

    f32x4 oacc[4];
#pragma unroll
    for (int cf = 0; cf < 4; ++cf) oacc[cf] = (f32x4){0.f, 0.f, 0.f, 0.f};
#pragma unroll
    for (int ks = 0; ks < 8; ++ks) {
        s16x8 ap = *(const s16x8*)&Ks[(w * 16 + (l & 15)) * 256 + ks * 32 + (l >> 4) * 8];
#pragma unroll
        for (int cf = 0; cf < 4; ++cf) {
            s16x8 bv = *(const s16x8*)&VTs[(cf * 16 + (l & 15)) * 256 + ks * 32 + (l >> 4) * 8];
            oacc[cf] = mfma16(ap, bv, oacc[cf]);
        }
    }
    size_t orow0 = (size_t)(b * 256 + qt * 64 + w * 16);
#pragma unroll
    for (int cf = 0; cf < 4; ++cf)
#pragma unroll
        for (int r = 0; r < 4; ++r) {
            int rr = (l >> 4) * 4 + r;
            obuf[(orow0 + rr) * 1024 + h * 64 + cf * 16 + (l & 15)] = f2b(oacc[cf][r]);
        }
}

// ---------- host ----------
extern "C" void kernel_launch(void* const* d_in, const int* in_sizes, int n_in,
                              void* d_out, int out_size, void* d_ws, size_t ws_size,
                              hipStream_t stream) {
    (void)in_sizes; (void)n_in; (void)out_size; (void)ws_size;
    const float* x         = (const float*)d_in[0];
    const int*   y         = (const int*)d_in[1];
    const int*   t         = (const int*)d_in[2];
    const float* proj_w    = (const float*)d_in[3];
    const float* proj_b    = (const float*)d_in[4];
    const float* pos_embed = (const float*)d_in[5];
    const float* emb_table = (const float*)d_in[6];
    const float* blk_mod_w = (const float*)d_in[7];
    const float* blk_mod_b = (const float*)d_in[8];
    const float* blk_wq    = (const float*)d_in[9];
    const float* blk_bq    = (const float*)d_in[10];
    const float* blk_wk    = (const float*)d_in[11];
    const float* blk_bk    = (const float*)d_in[12];
    const float* blk_wv    = (const float*)d_in[13];
    const float* blk_bv    = (const float*)d_in[14];
    const float* blk_wo    = (const float*)d_in[15];
    const float* blk_bo    = (const float*)d_in[16];
    const float* blk_f1w   = (const float*)d_in[17];
    const float* blk_f1b   = (const float*)d_in[18];
    const float* blk_f2w   = (const float*)d_in[19];
    const float* blk_f2b   = (const float*)d_in[20];
    const float* fin_mod_w = (const float*)d_in[21];
    const float* fin_mod_b = (const float*)d_in[22];
    const float* fin_out_w = (const float*)d_in[23];
    const float* fin_out_b = (const float*)d_in[24];
    float* out = (float*)d_out;

    char* ws = (char*)d_ws;
    size_t off = 0;
    auto alloc = [&](size_t bytes) -> char* {
        char* p = ws + off;
        off += (bytes + 255) & ~(size_t)255;
        return p;
    };
    float* xc    = (float*)alloc(8192ull * 1024 * 4);
    u16*   hx    = (u16*)alloc(8192ull * 1024 * 2);
    u16*   qkvb  = (u16*)alloc(8192ull * 3072 * 2);
    u16*   obufp = (u16*)alloc(8192ull * 1024 * 2);
    u16*   h1    = (u16*)alloc(8192ull * 4096 * 2);
    u16*   patchA= (u16*)alloc(8192ull * 256 * 2);
    float* cactF = (float*)alloc(32ull * 1024 * 4);
    float* modb  = (float*)alloc(32ull * 6144 * 4);
    float* fmod  = (float*)alloc(32ull * 2048 * 4);
    float* bqkv  = (float*)alloc(12ull * 3072 * 4);
    u16*   projT = (u16*)alloc(1024ull * 256 * 2);
    u16*   foT   = (u16*)alloc(256ull * 1024 * 2);
    u16*   qkvT  = (u16*)alloc(3072ull * 1024 * 2);
    u16*   woT   = (u16*)alloc(1024ull * 1024 * 2);
    u16*   f1T   = (u16*)alloc(4096ull * 1024 * 2);
    u16*   f2T   = (u16*)alloc(1024ull * 4096 * 2);

    patchify_kernel<<<8192, 256, 0, stream>>>(x, patchA);
    cact_kernel<<<32, 256, 0, stream>>>(t, y, emb_table, cactF);
    bcat_kernel<<<dim3(12, 3), 256, 0, stream>>>(blk_bq, blk_bk, blk_bv, bqkv);
    transpose_cvt64k<<<dim3(16, 4), 256, 0, stream>>>(proj_w, projT, 256, 1024);
    transpose_cvt64k<<<dim3(4, 16), 256, 0, stream>>>(fin_out_w, foT, 1024, 256);
    mod32_kernel<<<32, 256, 0, stream>>>(cactF, fin_mod_w, fin_mod_b, fmod, 2048);

    // tok = patchA @ proj_w + b + pos  -> xc f32   (M=8192,N=1024,K=256)
    gemm8<2><<<256, 512, 0, stream>>>(patchA, 256, projT, 256, 8192, 1024, 256,
                                      proj_b, xc, nullptr, 1024, pos_embed, nullptr, 0);

    for (int i = 0; i < 12; ++i) {
        transpose_layer<<<3072, 256, 0, stream>>>(
            blk_wq + (size_t)i * 1024 * 1024, blk_wk + (size_t)i * 1024 * 1024,
            blk_wv + (size_t)i * 1024 * 1024, blk_wo + (size_t)i * 1024 * 1024,
            blk_f1w + (size_t)i * 1024 * 4096, blk_f2w + (size_t)i * 4096 * 1024,
            qkvT, woT, f1T, f2T);

        // mod = c_act @ mod_w + mod_b   (32 x 6144), pure fp32
        mod32_kernel<<<96, 256, 0, stream>>>(cactF, blk_mod_w + (size_t)i * 1024 * 6144,
                                             blk_mod_b + (size_t)i * 6144, modb, 6144);
        // hx = ln(xc)*(1+sc_a)+sh_a
        ln_mod_kernel<<<8192, 256, 0, stream>>>(xc, modb, 6144, 0, 1024, hx);
        // qkv = hx @ [wq|wk|wv] + biases  -> bf16   (8-phase 256^2)
        gemm256_8ph<1><<<384, 512, 0, stream>>>(hx, 1024, qkvT, 1024, 8192, 3072, 1024,
                                                bqkv + (size_t)i * 3072, qkvb, 3072);
        attn_kernel<<<dim3(4, 16, 32), 256, 0, stream>>>(qkvb, obufp);
        // xc += g_a * (o @ wo + bo)
        gemm8<3><<<256, 512, 0, stream>>>(obufp, 1024, woT, 1024, 8192, 1024, 1024,
                                          blk_bo + (size_t)i * 1024, xc, nullptr, 1024,
                                          xc, modb, 2048);
        // hx = ln(xc)*(1+sc_m)+sh_m
        ln_mod_kernel<<<8192, 256, 0, stream>>>(xc, modb, 6144, 3072, 4096, hx);
        // h1 = gelu(hx @ f1 + b1)   (8-phase 256^2)
        gemm256_8ph<4><<<512, 512, 0, stream>>>(hx, 1024, f1T, 1024, 8192, 4096, 1024,
                                                blk_f1b + (size_t)i * 4096, h1, 4096);
        // xc += g_m * (h1 @ f2 + b2)
        gemm8<3><<<256, 512, 0, stream>>>(h1, 4096, f2T, 4096, 8192, 1024, 4096,
                                          blk_f2b + (size_t)i * 1024, xc, nullptr, 1024,
                                          xc, modb, 5120);
    }
    // final: hx = ln(xc)*(1+sc)+sh ; out = unpatchify(hx @ fin_out_w + b)
    ln_mod_kernel<<<8192, 256, 0, stream>>>(xc, fmod, 2048, 0, 1024, hx);
    gemm_fin<<<dim3(2, 64), 256, 0, stream>>>(hx, 1024, foT, 1024, 8192, 256, 1024,
                                              fin_out_b, out);
}

// Round 5
// 5576.034 us; speedup vs baseline: 1.1046x; 1.0926x over previous
//
#include <hip/hip_runtime.h>
#include <hip/hip_bf16.h>
#include <math.h>

typedef short s16x8 __attribute__((ext_vector_type(8)));
typedef float f32x4 __attribute__((ext_vector_type(4)));
typedef unsigned short u16;

#define BAR() __builtin_amdgcn_s_barrier()
#define PRIO1() __builtin_amdgcn_s_setprio(1)
#define PRIO0() __builtin_amdgcn_s_setprio(0)
#define VMCNT0() asm volatile("s_waitcnt vmcnt(0)" ::: "memory")

// ---------- helpers ----------
__device__ __forceinline__ u16 f2b(float f) {
    unsigned u = __builtin_bit_cast(unsigned, f);
    u += 0x7fffu + ((u >> 16) & 1u);           // round-to-nearest-even
    return (u16)(u >> 16);
}
__device__ __forceinline__ f32x4 mfma16(s16x8 a, s16x8 b, f32x4 c) {
    return __builtin_amdgcn_mfma_f32_16x16x32_bf16(a, b, c, 0, 0, 0);
}
__device__ __forceinline__ void gload16(const void* g, void* l) {
    __builtin_amdgcn_global_load_lds((const __attribute__((address_space(1))) unsigned*)g,
                                     (__attribute__((address_space(3))) unsigned*)l, 16, 0, 0);
}

// ---------- patchify: x (32,64,32,32) f32 -> patchA (8192,256) bf16 ----------
__global__ __launch_bounds__(256) void patchify_kernel(const float* __restrict__ x, u16* __restrict__ out) {
    int idx = blockIdx.x * 256 + threadIdx.x;
    int row = idx >> 8, col = idx & 255;
    int b = row >> 8, ll = row & 255, hp = ll >> 4, wp = ll & 15;
    int pp = col >> 6, d = col & 63;
    out[idx] = f2b(x[(size_t)((b * 64 + d) * 32 + hp * 2 + (pp >> 1)) * 32 + wp * 2 + (pp & 1)]);
}

// ---------- c_act = silu(timestep_emb + emb_table[y]) -> f32 (32,1024) ----------
__global__ __launch_bounds__(256) void cact_kernel(const int* __restrict__ t, const int* __restrict__ y,
                                                   const float* __restrict__ emb, float* __restrict__ cactF) {
    int b = blockIdx.x, tid = threadIdx.x;
    float tv = (float)t[b];
    int yb = y[b];
#pragma unroll
    for (int j = 0; j < 4; ++j) {
        int c = tid * 4 + j;
        int f = (c < 512) ? c : c - 512;
        float freq = __expf(-9.210340371976184f * (float)f * (1.f / 512.f));
        float ang = tv * freq;
        float v = (c < 512) ? cosf(ang) : sinf(ang);
        v += emb[(size_t)yb * 1024 + c];
        v = v / (1.f + __expf(-v));   // silu
        cactF[b * 1024 + c] = v;
    }
}

// ---------- concat q/k/v biases for all 12 layers -> (12,3072) f32 ----------
__global__ __launch_bounds__(256) void bcat_kernel(const float* __restrict__ bq, const float* __restrict__ bk,
                                                   const float* __restrict__ bv, float* __restrict__ out) {
    int lyr = blockIdx.x, j = blockIdx.y, tid = threadIdx.x;
    const float* src = (j == 0) ? bq : ((j == 1) ? bk : bv);
    float4 v = ((const float4*)(src + (size_t)lyr * 1024))[tid];
    ((float4*)(out + (size_t)lyr * 3072 + j * 1024))[tid] = v;
}

// ---------- mod32: out(32,N) = cactF(32,1024) @ W(1024,N) + bias, all f32 ----------
__global__ __launch_bounds__(256) void mod32_kernel(const float* __restrict__ cactF, const float* __restrict__ W,
                                                    const float* __restrict__ bias, float* __restrict__ out, int N) {
    __shared__ float cs[32 * 256];
    __shared__ float red[4 * 32 * 64];
    int tid = threadIdx.x, lane = tid & 63, kg = tid >> 6;
    int n = blockIdx.x * 64 + lane;
    float acc[32];
#pragma unroll
    for (int r = 0; r < 32; ++r) acc[r] = 0.f;
    for (int ch = 0; ch < 4; ++ch) {
        __syncthreads();
#pragma unroll
        for (int j = 0; j < 8; ++j) {
            int idx = tid * 4 + j * 1024;
            float4 v = *(const float4*)&cactF[(size_t)(idx >> 8) * 1024 + ch * 256 + (idx & 255)];
            *(float4*)&cs[idx] = v;
        }
        __syncthreads();
        const float* Wp = W + (size_t)(ch * 256 + kg * 64) * N + n;
        for (int kk = 0; kk < 64; kk += 4) {
            float w0 = Wp[(size_t)(kk + 0) * N];
            float w1 = Wp[(size_t)(kk + 1) * N];
            float w2 = Wp[(size_t)(kk + 2) * N];
            float w3 = Wp[(size_t)(kk + 3) * N];
            int kb = kg * 64 + kk;
#pragma unroll
            for (int r = 0; r < 32; ++r) {
                float4 cv = *(const float4*)&cs[r * 256 + kb];
                acc[r] += cv.x * w0 + cv.y * w1 + cv.z * w2 + cv.w * w3;
            }
        }
    }
#pragma unroll
    for (int r = 0; r < 32; ++r) red[(kg * 32 + r) * 64 + lane] = acc[r];
    __syncthreads();
    int r = tid >> 3, j0 = (tid & 7) * 8;
#pragma unroll
    for (int jj = 0; jj < 8; ++jj) {
        int nn = j0 + jj;
        float s = red[(0 * 32 + r) * 64 + nn] + red[(1 * 32 + r) * 64 + nn] +
                  red[(2 * 32 + r) * 64 + nn] + red[(3 * 32 + r) * 64 + nn];
        out[(size_t)r * N + blockIdx.x * 64 + nn] = s + bias[blockIdx.x * 64 + nn];
    }
}

// ---------- 64x64 transpose + f32->bf16 convert body ----------
__device__ __forceinline__ void tpose_body(float (*tile)[65], const float* __restrict__ in,
                                           u16* __restrict__ out, int R, int C, int r0, int c0, int tid) {
    int rr = tid >> 4, cc = (tid & 15) * 4;
#pragma unroll
    for (int j = 0; j < 4; ++j) {
        float4 v = *(const float4*)&in[(size_t)(r0 + j * 16 + rr) * C + c0 + cc];
        tile[j * 16 + rr][cc]     = v.x;
        tile[j * 16 + rr][cc + 1] = v.y;
        tile[j * 16 + rr][cc + 2] = v.z;
        tile[j * 16 + rr][cc + 3] = v.w;
    }
    __syncthreads();
    int oc = tid >> 3, r8 = (tid & 7) * 8;
#pragma unroll
    for (int j = 0; j < 2; ++j) {
        int ocl = j * 32 + oc;
        s16x8 vv;
#pragma unroll
        for (int e = 0; e < 8; ++e) vv[e] = (short)f2b(tile[r8 + e][ocl]);
        *(s16x8*)&out[(size_t)(c0 + ocl) * R + r0 + r8] = vv;
    }
}

__global__ __launch_bounds__(256) void transpose_cvt64k(const float* __restrict__ in, u16* __restrict__ out,
                                                        int R, int C) {
    __shared__ float tile[64][65];
    tpose_body(tile, in, out, R, C, blockIdx.y * 64, blockIdx.x * 64, threadIdx.x);
}

// ---------- one layer's attention/MLP weights, transposed+converted ----------
__global__ __launch_bounds__(256) void transpose_layer(
    const float* __restrict__ wq, const float* __restrict__ wk,
    const float* __restrict__ wv, const float* __restrict__ wo, const float* __restrict__ f1,
    const float* __restrict__ f2,
    u16* __restrict__ qkvT, u16* __restrict__ woT, u16* __restrict__ f1T, u16* __restrict__ f2T) {
    __shared__ float tile[64][65];
    int bid = blockIdx.x, tid = threadIdx.x;
    const float* src; u16* dst; int R, C, tloc;
    if (bid < 256)       { src = wq; dst = qkvT;               R = 1024; C = 1024; tloc = bid; }
    else if (bid < 512)  { src = wk; dst = qkvT + 1024 * 1024; R = 1024; C = 1024; tloc = bid - 256; }
    else if (bid < 768)  { src = wv; dst = qkvT + 2048 * 1024; R = 1024; C = 1024; tloc = bid - 512; }
    else if (bid < 1024) { src = wo; dst = woT;                R = 1024; C = 1024; tloc = bid - 768; }
    else if (bid < 2048) { src = f1; dst = f1T;                R = 1024; C = 4096; tloc = bid - 1024; }
    else                 { src = f2; dst = f2T;                R = 4096; C = 1024; tloc = bid - 2048; }
    int tx = C >> 6;
    int ty = tloc / tx, txi = tloc - ty * tx;
    tpose_body(tile, src, dst, R, C, ty * 64, txi * 64, tid);
}

// ---------- LayerNorm + modulate: hx = ln(x)*(1+sc)+sh -> bf16 ----------
__global__ __launch_bounds__(256) void ln_mod_kernel(const float* __restrict__ x, const float* __restrict__ modv,
                                                     int mod_ld, int sh_off, int sc_off, u16* __restrict__ out) {
    int row = blockIdx.x, tid = threadIdx.x, b = row >> 8;
    float4 xv = ((const float4*)(x + (size_t)row * 1024))[tid];
    float s = xv.x + xv.y + xv.z + xv.w;
    float s2 = xv.x * xv.x + xv.y * xv.y + xv.z * xv.z + xv.w * xv.w;
#pragma unroll
    for (int d = 1; d < 64; d <<= 1) { s += __shfl_xor(s, d); s2 += __shfl_xor(s2, d); }
    __shared__ float red[8];
    int w = tid >> 6;
    if ((tid & 63) == 0) { red[w] = s; red[4 + w] = s2; }
    __syncthreads();
    s = red[0] + red[1] + red[2] + red[3];
    s2 = red[4] + red[5] + red[6] + red[7];
    float mu = s * (1.f / 1024.f);
    float rs = rsqrtf(s2 * (1.f / 1024.f) - mu * mu + 1e-5f);
    const float* shp = modv + (size_t)b * mod_ld + sh_off;
    const float* scp = modv + (size_t)b * mod_ld + sc_off;
    float4 sh4 = ((const float4*)shp)[tid];
    float4 sc4 = ((const float4*)scp)[tid];
    u16 o0 = f2b((xv.x - mu) * rs * (1.f + sc4.x) + sh4.x);
    u16 o1 = f2b((xv.y - mu) * rs * (1.f + sc4.y) + sh4.y);
    u16 o2 = f2b((xv.z - mu) * rs * (1.f + sc4.z) + sh4.z);
    u16 o3 = f2b((xv.w - mu) * rs * (1.f + sc4.w) + sh4.w);
    unsigned long long pk = (unsigned long long)o0 | ((unsigned long long)o1 << 16) |
                            ((unsigned long long)o2 << 32) | ((unsigned long long)o3 << 48);
    *(unsigned long long*)&out[(size_t)row * 1024 + tid * 4] = pk;
}

// =====================================================================
// gemm8: pipelined GEMM, BM=256 x BN=128, BK=64, 512 thr (8 waves 4x2),
// 3 LDS buffers (144KB), counted vmcnt(3), slot swizzle s ^= r&7 both sides.
// C = A(MxK,bf16) @ Bt(NxK,bf16)^T. M%256==0, N%128==0, K%64==0, grid%8==0.
// EPI: 1 bf16+bias; 2 f32+bias+pos; 3 residual gate; 4 gelu bf16
// =====================================================================
template <int EPI>
__global__ __launch_bounds__(512, 1) void gemm8(
    const u16* __restrict__ A, int lda, const u16* __restrict__ Bt, int ldb,
    int M, int N, int K, const float* __restrict__ bias,
    float* __restrict__ outF, u16* __restrict__ outB, int ldc,
    const float* __restrict__ aux1, const float* __restrict__ aux2, int gateOff) {
    __shared__ u16 As[3][256 * 64];
    __shared__ u16 Bs[3][128 * 64];

    const int tid = threadIdx.x, w = tid >> 6, l = tid & 63;
    const int wm = w >> 1, wn = w & 1;

    const int nbn = N >> 7;
    const int orig = blockIdx.x;
    const int cpx = gridDim.x >> 3;
    const int wg = (orig & 7) * cpx + (orig >> 3);   // XCD-chunked swizzle (grid%8==0)
    const int bm = wg / nbn, bn = wg - bm * nbn;
    const int row0 = bm << 8, col0 = bn << 7;

    const int NT = K >> 6;

    const int srow = tid >> 3, sslot = tid & 7;
    const int ksl = sslot ^ (srow & 7);
    const u16* gA = A + (size_t)(row0 + srow) * lda + ksl * 8;
    const u16* gB = Bt + (size_t)(col0 + srow) * ldb + ksl * 8;
    const int lOff = srow * 64 + sslot * 8;

    const int fr = l & 15, fg = l >> 4;
    const int arow = wm * 64 + fr;
    const int brow = wn * 64 + fr;

    f32x4 acc[4][4];
#pragma unroll
    for (int m = 0; m < 4; ++m)
#pragma unroll
        for (int n = 0; n < 4; ++n) acc[m][n] = (f32x4){0.f, 0.f, 0.f, 0.f};

    {
        u16* a0 = &As[0][lOff];
        u16* b0 = &Bs[0][lOff];
#pragma unroll
        for (int a = 0; a < 4; ++a) gload16(gA + (size_t)a * 64 * lda, a0 + a * 4096);
#pragma unroll
        for (int b = 0; b < 2; ++b) gload16(gB + (size_t)b * 64 * ldb, b0 + b * 4096);
        if (NT > 1) {
            u16* a1 = &As[1][lOff];
#pragma unroll
            for (int a = 0; a < 3; ++a) gload16(gA + (size_t)a * 64 * lda + 64, a1 + a * 4096);
        }
    }
    if (NT > 1) { asm volatile("s_waitcnt vmcnt(3)" ::: "memory"); }
    else        { VMCNT0(); }
    BAR();
    __builtin_amdgcn_sched_barrier(0);

    int q = 0;
    for (int t = 0; t < NT; ++t) {
        const u16* ca = As[q];
        const u16* cb = Bs[q];
        const int q1 = (q == 2) ? 0 : q + 1;
        const int q2 = (q1 == 2) ? 0 : q1 + 1;

        s16x8 af[4][2], bf[4][2];
#pragma unroll
        for (int m = 0; m < 4; ++m) {
            int r = arow + m * 16;
            af[m][0] = *(const s16x8*)(ca + r * 64 + ((fg     ^ (r & 7)) * 8));
            af[m][1] = *(const s16x8*)(ca + r * 64 + (((4 + fg) ^ (r & 7)) * 8));
        }
#pragma unroll
        for (int n = 0; n < 2; ++n) {
            int r = brow + n * 16;
            bf[n][0] = *(const s16x8*)(cb + r * 64 + ((fg     ^ (r & 7)) * 8));
            bf[n][1] = *(const s16x8*)(cb + r * 64 + (((4 + fg) ^ (r & 7)) * 8));
        }
        if (t + 1 < NT) {
            gload16(gA + (size_t)(3 * 64) * lda + (size_t)(t + 1) * 64, &As[q1][lOff] + 3 * 4096);
            gload16(gB + (size_t)(t + 1) * 64, &Bs[q1][lOff]);
            gload16(gB + (size_t)(1 * 64) * ldb + (size_t)(t + 1) * 64, &Bs[q1][lOff] + 4096);
        }
        BAR(); PRIO1();
#pragma unroll
        for (int m = 0; m < 4; ++m)
#pragma unroll
            for (int n = 0; n < 2; ++n) {
                acc[m][n] = mfma16(af[m][0], bf[n][0], acc[m][n]);
                acc[m][n] = mfma16(af[m][1], bf[n][1], acc[m][n]);
            }
        PRIO0(); BAR();
#pragma unroll
        for (int n = 0; n < 2; ++n) {
            int r = brow + (n + 2) * 16;
            bf[n + 2][0] = *(const s16x8*)(cb + r * 64 + ((fg     ^ (r & 7)) * 8));
            bf[n + 2][1] = *(const s16x8*)(cb + r * 64 + (((4 + fg) ^ (r & 7)) * 8));
        }
        if (t + 2 < NT) {
#pragma unroll
            for (int a = 0; a < 3; ++a)
                gload16(gA + (size_t)a * 64 * lda + (size_t)(t + 2) * 64, &As[q2][lOff] + a * 4096);
        }
        BAR(); PRIO1();
#pragma unroll
        for (int m = 0; m < 4; ++m)
#pragma unroll
            for (int n = 2; n < 4; ++n) {
                acc[m][n] = mfma16(af[m][0], bf[n][0], acc[m][n]);
                acc[m][n] = mfma16(af[m][1], bf[n][1], acc[m][n]);
            }
        PRIO0();
        if (t < NT - 2)       { asm volatile("s_waitcnt vmcnt(3)" ::: "memory"); }
        else if (t == NT - 2) { VMCNT0(); }
        if (t < NT - 1) {
            BAR();
            __builtin_amdgcn_sched_barrier(0);
        }
        q = q1;
    }

    const int erow = row0 + wm * 64 + fg * 4;
    const int ecol = col0 + wn * 64 + fr;
#pragma unroll
    for (int m = 0; m < 4; ++m) {
#pragma unroll
        for (int n = 0; n < 4; ++n) {
#pragma unroll
            for (int r = 0; r < 4; ++r) {
                int row = erow + m * 16 + r;
                int col = ecol + n * 16;
                float v = acc[m][n][r];
                if constexpr (EPI == 1) {
                    outB[(size_t)row * ldc + col] = f2b(v + bias[col]);
                } else if constexpr (EPI == 2) {
                    outF[(size_t)row * ldc + col] = v + bias[col] + aux1[(size_t)(row & 255) * 1024 + col];
                } else if constexpr (EPI == 3) {
                    outF[(size_t)row * ldc + col] =
                        aux1[(size_t)row * ldc + col] +
                        aux2[(size_t)(row >> 8) * 6144 + gateOff + col] * (v + bias[col]);
                } else {  // EPI == 4: exact gelu -> bf16
                    float xg = v + bias[col];
                    outB[(size_t)row * ldc + col] = f2b(0.5f * xg * (1.f + erff(xg * 0.70710678118654752f)));
                }
            }
        }
    }
}

// ---------- small GEMM (m97-style): final unpatchify only ----------
__global__ __launch_bounds__(256, 2) void gemm_fin(
    const u16* __restrict__ A, int lda, const u16* __restrict__ Bt, int ldb,
    int M, int N, int K, const float* __restrict__ bias, float* outF) {
    __shared__ u16 Asl[128 * 32];
    __shared__ u16 Bsl[128 * 32];
    const int tid = threadIdx.x, w = tid >> 6, l = tid & 63;
    const int row0 = blockIdx.y * 128, col0 = blockIdx.x * 128;
    const int wm = w >> 1, wn = w & 1;

    f32x4 acc[4][4];
#pragma unroll
    for (int m = 0; m < 4; ++m)
#pragma unroll
        for (int n = 0; n < 4; ++n) acc[m][n] = (f32x4){0.f, 0.f, 0.f, 0.f};

    const int rA0 = w * 16 + (l >> 2), rA1 = rA0 + 64;
    const int kc = (l & 3) * 8;
    const u16* a0 = A + (size_t)(row0 + rA0) * lda + kc;
    const u16* a1 = A + (size_t)(row0 + rA1) * lda + kc;
    const u16* b0 = Bt + (size_t)(col0 + rA0) * ldb + kc;
    const u16* b1 = Bt + (size_t)(col0 + rA1) * ldb + kc;
    u16* la0 = &Asl[rA0 * 32 + kc];
    u16* la1 = &Asl[rA1 * 32 + kc];
    u16* lb0 = &Bsl[rA0 * 32 + kc];
    u16* lb1 = &Bsl[rA1 * 32 + kc];

    for (int k0 = 0; k0 < K; k0 += 32) {
        __syncthreads();
        gload16(a0 + k0, la0);
        gload16(a1 + k0, la1);
        gload16(b0 + k0, lb0);
        gload16(b1 + k0, lb1);
        __syncthreads();
        s16x8 af[4], bfr[4];
#pragma unroll
        for (int m = 0; m < 4; ++m)
            af[m] = *(const s16x8*)&Asl[(wm * 64 + m * 16 + (l & 15)) * 32 + (l >> 4) * 8];
#pragma unroll
        for (int n = 0; n < 4; ++n)
            bfr[n] = *(const s16x8*)&Bsl[(wn * 64 + n * 16 + (l & 15)) * 32 + (l >> 4) * 8];
#pragma unroll
        for (int m = 0; m < 4; ++m)
#pragma unroll
            for (int n = 0; n < 4; ++n) acc[m][n] = mfma16(af[m], bfr[n], acc[m][n]);
    }

#pragma unroll
    for (int m = 0; m < 4; ++m) {
#pragma unroll
        for (int n = 0; n < 4; ++n) {
#pragma unroll
            for (int r = 0; r < 4; ++r) {
                int row = row0 + wm * 64 + m * 16 + (l >> 4) * 4 + r;
                int col = col0 + wn * 64 + n * 16 + (l & 15);
                float xg = acc[m][n][r] + bias[col];
                int bb = row >> 8, ll = row & 255, hp = ll >> 4, wp = ll & 15;
                int pp = col >> 6, d = col & 63;
                outF[(size_t)((bb * 64 + d) * 32 + hp * 2 + (pp >> 1)) * 32 + wp * 2 + (pp & 1)] = xg;
            }
        }
    }
}

// ---------- attention: qkv (8192,3072) bf16 -> obuf (8192,1024) bf16 ----------
__global__ __launch_bounds__(256, 2) void attn_kernel(const u16* __restrict__ qkv, u16* __restrict__ obuf) {
    __shared__ u16 Qs[64 * 64];
    __shared__ u16 Ks[256 * 64];    // reused later as P [qrow][ktok]
    __shared__ u16 VTs[64 * 256];
    int qt = blockIdx.x, h = blockIdx.y, b = blockIdx.z;
    int tid = threadIdx.x, w = tid >> 6, l = tid & 63;
    size_t base = (size_t)b * 256 * 3072;

    {
        int r = tid >> 2;
#pragma unroll
        for (int j = 0; j < 2; ++j) {
            int sg = (tid & 3) + j * 4;
            *(s16x8*)&Qs[r * 64 + sg * 8] =
                *(const s16x8*)&qkv[base + (size_t)(qt * 64 + r) * 3072 + h * 64 + sg * 8];
        }
    }
#pragma unroll
    for (int j = 0; j < 8; ++j) {
        int i = tid + j * 256;
        int r = i >> 3, sg = i & 7;
        *(s16x8*)&Ks[r * 64 + sg * 8] =
            *(const s16x8*)&qkv[base + (size_t)r * 3072 + 1024 + h * 64 + sg * 8];
    }
#pragma unroll
    for (int j = 0; j < 8; ++j) {
        int i = tid + j * 256;
        int r = i >> 3, sg = i & 7;
        s16x8 v = *(const s16x8*)&qkv[base + (size_t)r * 3072 + 2048 + h * 64 + sg * 8];
#pragma unroll
        for (int e = 0; e < 8; ++e) VTs[(sg * 8 + e) * 256 + r] = ((const u16*)&v)[e];
    }
    __syncthreads();

    s16x8 aq0 = *(const s16x8*)&Qs[(w * 16 + (l & 15)) * 64 + (l >> 4) * 8];
    s16x8 aq1 = *(const s16x8*)&Qs[(w * 16 + (l & 15)) * 64 + 32 + (l >> 4) * 8];
    f32x4 sf[16];
#pragma unroll
    for (int cf = 0; cf < 16; ++cf) {
        f32x4 a = (f32x4){0.f, 0.f, 0.f, 0.f};
        s16x8 bk0 = *(const s16x8*)&Ks[(cf * 16 + (l & 15)) * 64 + (l >> 4) * 8];
        s16x8 bk1 = *(const s16x8*)&Ks[(cf * 16 + (l & 15)) * 64 + 32 + (l >> 4) * 8];
        a = mfma16(aq0, bk0, a);
        a = mfma16(aq1, bk1, a);
        sf[cf] = a * 0.125f;
    }
    __syncthreads();

#pragma unroll
    for (int r = 0; r < 4; ++r) {
        float m = -1e30f;
#pragma unroll
        for (int cf = 0; cf < 16; ++cf) m = fmaxf(m, sf[cf][r]);
#pragma unroll
        for (int d = 1; d < 16; d <<= 1) m = fmaxf(m, __shfl_xor(m, d));
        float sm = 0.f;
#pragma unroll
        for (int cf = 0; cf < 16; ++cf) { float e = __expf(sf[cf][r] - m); sf[cf][r] = e; sm += e; }
#pragma unroll
        for (int d = 1; d < 16; d <<= 1) sm += __shfl_xor(sm, d);
        float inv = 1.f / sm;
        int rl = w * 16 + (l >> 4) * 4 + r;
#pragma unroll
        for (int cf = 0; cf < 16; ++cf) Ks[rl * 256 + cf * 16 + (l & 15)] = f2b(sf[cf][r] * inv);
    }
    __syncthreads();

    f32x4 oacc[4];
#pragma unroll
    for (int cf = 0; cf < 4; ++cf) oacc[cf] = (f32x4){0.f, 0.f, 0.f, 0.f};
#pragma unroll
    for (int ks = 0; ks < 8; ++ks) {
        s16x8 ap = *(const s16x8*)&Ks[(w * 16 + (l & 15)) * 256 + ks * 32 + (l >> 4) * 8];
#pragma unroll
        for (int cf = 0; cf < 4; ++cf) {
            s16x8 bv = *(const s16x8*)&VTs[(cf * 16 + (l & 15)) * 256 + ks * 32 + (l >> 4) * 8];
            oacc[cf] = mfma16(ap, bv, oacc[cf]);
        }
    }
    size_t orow0 = (size_t)(b * 256 + qt * 64 + w * 16);
#pragma unroll
    for (int cf = 0; cf < 4; ++cf)
#pragma unroll
        for (int r = 0; r < 4; ++r) {
            int rr = (l >> 4) * 4 + r;
            obuf[(orow0 + rr) * 1024 + h * 64 + cf * 16 + (l & 15)] = f2b(oacc[cf][r]);
        }
}

// ---------- host ----------
extern "C" void kernel_launch(void* const* d_in, const int* in_sizes, int n_in,
                              void* d_out, int out_size, void* d_ws, size_t ws_size,
                              hipStream_t stream) {
    (void)in_sizes; (void)n_in; (void)out_size; (void)ws_size;
    const float* x         = (const float*)d_in[0];
    const int*   y         = (const int*)d_in[1];
    const int*   t         = (const int*)d_in[2];
    const float* proj_w    = (const float*)d_in[3];
    const float* proj_b    = (const float*)d_in[4];
    const float* pos_embed = (const float*)d_in[5];
    const float* emb_table = (const float*)d_in[6];
    const float* blk_mod_w = (const float*)d_in[7];
    const float* blk_mod_b = (const float*)d_in[8];
    const float* blk_wq    = (const float*)d_in[9];
    const float* blk_bq    = (const float*)d_in[10];
    const float* blk_wk    = (const float*)d_in[11];
    const float* blk_bk    = (const float*)d_in[12];
    const float* blk_wv    = (const float*)d_in[13];
    const float* blk_bv    = (const float*)d_in[14];
    const float* blk_wo    = (const float*)d_in[15];
    const float* blk_bo    = (const float*)d_in[16];
    const float* blk_f1w   = (const float*)d_in[17];
    const float* blk_f1b   = (const float*)d_in[18];
    const float* blk_f2w   = (const float*)d_in[19];
    const float* blk_f2b   = (const float*)d_in[20];
    const float* fin_mod_w = (const float*)d_in[21];
    const float* fin_mod_b = (const float*)d_in[22];
    const float* fin_out_w = (const float*)d_in[23];
    const float* fin_out_b = (const float*)d_in[24];
    float* out = (float*)d_out;

    char* ws = (char*)d_ws;
    size_t off = 0;
    auto alloc = [&](size_t bytes) -> char* {
        char* p = ws + off;
        off += (bytes + 255) & ~(size_t)255;
        return p;
    };
    float* xc    = (float*)alloc(8192ull * 1024 * 4);
    u16*   hx    = (u16*)alloc(8192ull * 1024 * 2);
    u16*   qkvb  = (u16*)alloc(8192ull * 3072 * 2);
    u16*   obufp = (u16*)alloc(8192ull * 1024 * 2);
    u16*   h1    = (u16*)alloc(8192ull * 4096 * 2);
    u16*   patchA= (u16*)alloc(8192ull * 256 * 2);
    float* cactF = (float*)alloc(32ull * 1024 * 4);
    float* modb  = (float*)alloc(32ull * 6144 * 4);
    float* fmod  = (float*)alloc(32ull * 2048 * 4);
    float* bqkv  = (float*)alloc(12ull * 3072 * 4);
    u16*   projT = (u16*)alloc(1024ull * 256 * 2);
    u16*   foT   = (u16*)alloc(256ull * 1024 * 2);
    u16*   qkvT  = (u16*)alloc(3072ull * 1024 * 2);
    u16*   woT   = (u16*)alloc(1024ull * 1024 * 2);
    u16*   f1T   = (u16*)alloc(4096ull * 1024 * 2);
    u16*   f2T   = (u16*)alloc(1024ull * 4096 * 2);

    patchify_kernel<<<8192, 256, 0, stream>>>(x, patchA);
    cact_kernel<<<32, 256, 0, stream>>>(t, y, emb_table, cactF);
    bcat_kernel<<<dim3(12, 3), 256, 0, stream>>>(blk_bq, blk_bk, blk_bv, bqkv);
    transpose_cvt64k<<<dim3(16, 4), 256, 0, stream>>>(proj_w, projT, 256, 1024);
    transpose_cvt64k<<<dim3(4, 16), 256, 0, stream>>>(fin_out_w, foT, 1024, 256);
    mod32_kernel<<<32, 256, 0, stream>>>(cactF, fin_mod_w, fin_mod_b, fmod, 2048);

    // tok = patchA @ proj_w + b + pos  -> xc f32   (M=8192,N=1024,K=256)
    gemm8<2><<<256, 512, 0, stream>>>(patchA, 256, projT, 256, 8192, 1024, 256,
                                      proj_b, xc, nullptr, 1024, pos_embed, nullptr, 0);

    for (int i = 0; i < 12; ++i) {
        transpose_layer<<<3072, 256, 0, stream>>>(
            blk_wq + (size_t)i * 1024 * 1024, blk_wk + (size_t)i * 1024 * 1024,
            blk_wv + (size_t)i * 1024 * 1024, blk_wo + (size_t)i * 1024 * 1024,
            blk_f1w + (size_t)i * 1024 * 4096, blk_f2w + (size_t)i * 4096 * 1024,
            qkvT, woT, f1T, f2T);

        // mod = c_act @ mod_w + mod_b   (32 x 6144), pure fp32
        mod32_kernel<<<96, 256, 0, stream>>>(cactF, blk_mod_w + (size_t)i * 1024 * 6144,
                                             blk_mod_b + (size_t)i * 6144, modb, 6144);
        // hx = ln(xc)*(1+sc_a)+sh_a
        ln_mod_kernel<<<8192, 256, 0, stream>>>(xc, modb, 6144, 0, 1024, hx);
        // qkv = hx @ [wq|wk|wv] + biases  -> bf16
        gemm8<1><<<768, 512, 0, stream>>>(hx, 1024, qkvT, 1024, 8192, 3072, 1024,
                                          bqkv + (size_t)i * 3072, nullptr, qkvb, 3072,
                                          nullptr, nullptr, 0);
        attn_kernel<<<dim3(4, 16, 32), 256, 0, stream>>>(qkvb, obufp);
        // xc += g_a * (o @ wo + bo)
        gemm8<3><<<256, 512, 0, stream>>>(obufp, 1024, woT, 1024, 8192, 1024, 1024,
                                          blk_bo + (size_t)i * 1024, xc, nullptr, 1024,
                                          xc, modb, 2048);
        // hx = ln(xc)*(1+sc_m)+sh_m
        ln_mod_kernel<<<8192, 256, 0, stream>>>(xc, modb, 6144, 3072, 4096, hx);
        // h1 = gelu(hx @ f1 + b1)
        gemm8<4><<<1024, 512, 0, stream>>>(hx, 1024, f1T, 1024, 8192, 4096, 1024,
                                           blk_f1b + (size_t)i * 4096, nullptr, h1, 4096,
                                           nullptr, nullptr, 0);
        // xc += g_m * (h1 @ f2 + b2)
        gemm8<3><<<256, 512, 0, stream>>>(h1, 4096, f2T, 4096, 8192, 1024, 4096,
                                          blk_f2b + (size_t)i * 1024, xc, nullptr, 1024,
                                          xc, modb, 5120);
    }
    // final: hx = ln(xc)*(1+sc)+sh ; out = unpatchify(hx @ fin_out_w + b)
    ln_mod_kernel<<<8192, 256, 0, stream>>>(xc, fmod, 2048, 0, 1024, hx);
    gemm_fin<<<dim3(2, 64), 256, 0, stream>>>(hx, 1024, foT, 1024, 8192, 256, 1024,
                                              fin_out_b, out);
}